// Round 6
// baseline (501.007 us; speedup 1.0000x reference)
//
#include <hip/hip_runtime.h>

#define N_NODES 100000
#define N_EDGES 1600000
#define IN_C 256
#define HID 128
#define NEG_SLOPE 0.2f
#define BN_EPS 1e-5f
#define NBUCK 391          // ceil(N_NODES/256): bucket b covers dst [b*256,(b+1)*256)
#define NPART 391          // ceil(N_EDGES/4096) partition tiles
#define PART_E 4096        // edges per partition block
#define BPAD 5120          // padded per-bucket staging stride (mean 4096 + 16 sigma)
#define ELEM_BLOCKS 2048   // grid-stride blocks for elementwise BN kernels

typedef unsigned int uint32;
typedef __attribute__((ext_vector_type(8))) short bf16x8;
typedef __attribute__((ext_vector_type(4))) float f32x4;

__device__ __forceinline__ float lrelu(float x) { return x > 0.f ? x : NEG_SLOPE * x; }

__device__ __forceinline__ unsigned short f2bf(float f) {
    uint32 u = __float_as_uint(f);
    u += 0x7fffu + ((u >> 16) & 1u);
    return (unsigned short)(u >> 16);
}
__device__ __forceinline__ float bf2f(unsigned short h) {
    return __uint_as_float(((uint32)h) << 16);
}
__device__ __forceinline__ float bflo(uint32 v) { return __uint_as_float(v << 16); }
__device__ __forceinline__ float bfhi(uint32 v) { return __uint_as_float(v & 0xffff0000u); }
__device__ __forceinline__ uint32 packbf(float a, float b) {
    return (uint32)f2bf(a) | ((uint32)f2bf(b) << 16);
}

// ---------------- transpose both W + init (block 0) ----------------
__global__ void k_transpose_all(const float* __restrict__ W1, const float* __restrict__ W2,
                                unsigned short* __restrict__ Wt1,
                                unsigned short* __restrict__ Wt2,
                                int* __restrict__ gcursor, float* __restrict__ bnacc,
                                int* __restrict__ row_ptr) {
    int t = threadIdx.x;
    if (blockIdx.x == 0) {
        for (int i = t; i < NBUCK + 1; i += 256) gcursor[i] = 0;
        bnacc[t] = 0.f;
        bnacc[256 + t] = 0.f;
        if (t == 0) row_ptr[N_NODES] = N_EDGES;
    }
    int idx = blockIdx.x * 256 + t;
    if (idx < IN_C * 128) {
        int k = idx >> 7, n = idx & 127;
        Wt1[n * IN_C + k] = f2bf(W1[idx]);
    } else {
        idx -= IN_C * 128;
        if (idx < HID * 128) {
            int k = idx >> 7, n = idx & 127;
            Wt2[n * HID + k] = f2bf(W2[idx]);
        }
    }
}

// ---------------- MFMA GEMM, register-prefetch pipelined ----------------
// ATT:   fuse GAT attention coefficient dot-products into the epilogue.
// STATS: fuse BN column stats (sum, sumsq) into the epilogue.
template <bool AF32, bool OUTF32, bool ATT, bool STATS>
__global__ __launch_bounds__(256) void k_gemm(const void* __restrict__ Av,
                                              const unsigned short* __restrict__ Wt,
                                              void* __restrict__ Out, int K,
                                              const float* __restrict__ att_s,
                                              const float* __restrict__ att_d,
                                              float* __restrict__ a_src,
                                              float* __restrict__ a_dst,
                                              float* __restrict__ bnst) {
    __shared__ unsigned short As[128 * 72];
    __shared__ unsigned short Bs[128 * 72];
    const int t = threadIdx.x;
    const int n0 = blockIdx.x * 128;
    const int wv = t >> 6, lane = t & 63;
    const int wy = wv >> 1, wx = wv & 1;
    const int lm = lane & 15, lg = lane >> 4;
    const float* Af = (const float*)Av;
    const unsigned short* Ah = (const unsigned short*)Av;

    f32x4 acc[4][4];
#pragma unroll
    for (int i = 0; i < 4; ++i)
#pragma unroll
        for (int j = 0; j < 4; ++j) acc[i][j] = (f32x4){0.f, 0.f, 0.f, 0.f};

    float4 afp[8];
    uint4 ahp[4];
    uint4 bvp[4];

    if (AF32) {
#pragma unroll
        for (int p = 0; p < 8; ++p) {
            int idx = p * 256 + t, row = idx >> 4, c4 = idx & 15, gn = n0 + row;
            afp[p] = (gn < N_NODES) ? *(const float4*)&Af[(size_t)gn * K + c4 * 4]
                                    : make_float4(0.f, 0.f, 0.f, 0.f);
        }
    } else {
#pragma unroll
        for (int p = 0; p < 4; ++p) {
            int idx = p * 256 + t, row = idx >> 3, c = idx & 7, gn = n0 + row;
            ahp[p] = (gn < N_NODES) ? *(const uint4*)&Ah[(size_t)gn * K + c * 8]
                                    : make_uint4(0, 0, 0, 0);
        }
    }
#pragma unroll
    for (int p = 0; p < 4; ++p) {
        int idx = p * 256 + t, n = idx >> 3, c = idx & 7;
        bvp[p] = *(const uint4*)&Wt[(size_t)n * K + c * 8];
    }

    for (int kc = 0; kc < K; kc += 64) {
        if (AF32) {
#pragma unroll
            for (int p = 0; p < 8; ++p) {
                int idx = p * 256 + t, row = idx >> 4, c4 = idx & 15;
                ushort4 b;
                b.x = f2bf(afp[p].x); b.y = f2bf(afp[p].y);
                b.z = f2bf(afp[p].z); b.w = f2bf(afp[p].w);
                *(ushort4*)&As[row * 72 + c4 * 4] = b;
            }
        } else {
#pragma unroll
            for (int p = 0; p < 4; ++p) {
                int idx = p * 256 + t, row = idx >> 3, c = idx & 7;
                *(uint4*)&As[row * 72 + c * 8] = ahp[p];
            }
        }
#pragma unroll
        for (int p = 0; p < 4; ++p) {
            int idx = p * 256 + t, n = idx >> 3, c = idx & 7;
            *(uint4*)&Bs[n * 72 + c * 8] = bvp[p];
        }
        __syncthreads();
        int kn = kc + 64;
        if (kn < K) {
            if (AF32) {
#pragma unroll
                for (int p = 0; p < 8; ++p) {
                    int idx = p * 256 + t, row = idx >> 4, c4 = idx & 15, gn = n0 + row;
                    afp[p] = (gn < N_NODES) ? *(const float4*)&Af[(size_t)gn * K + kn + c4 * 4]
                                            : make_float4(0.f, 0.f, 0.f, 0.f);
                }
            } else {
#pragma unroll
                for (int p = 0; p < 4; ++p) {
                    int idx = p * 256 + t, row = idx >> 3, c = idx & 7, gn = n0 + row;
                    ahp[p] = (gn < N_NODES) ? *(const uint4*)&Ah[(size_t)gn * K + kn + c * 8]
                                            : make_uint4(0, 0, 0, 0);
                }
            }
#pragma unroll
            for (int p = 0; p < 4; ++p) {
                int idx = p * 256 + t, n = idx >> 3, c = idx & 7;
                bvp[p] = *(const uint4*)&Wt[(size_t)n * K + kn + c * 8];
            }
        }
#pragma unroll
        for (int ks = 0; ks < 2; ++ks) {
            bf16x8 af[4], bfr[4];
#pragma unroll
            for (int i = 0; i < 4; ++i)
                af[i] = *(const bf16x8*)&As[(wy * 64 + i * 16 + lm) * 72 + ks * 32 + lg * 8];
#pragma unroll
            for (int j = 0; j < 4; ++j)
                bfr[j] = *(const bf16x8*)&Bs[(wx * 64 + j * 16 + lm) * 72 + ks * 32 + lg * 8];
#pragma unroll
            for (int i = 0; i < 4; ++i)
#pragma unroll
                for (int j = 0; j < 4; ++j)
                    acc[i][j] = __builtin_amdgcn_mfma_f32_16x16x32_bf16(af[i], bfr[j],
                                                                        acc[i][j], 0, 0, 0);
        }
        __syncthreads();
    }

    // ---- epilogue ----
    float as_w[4], ad_w[4];
    if (ATT) {
#pragma unroll
        for (int j = 0; j < 4; ++j) {
            int col = wx * 64 + j * 16 + lm;
            as_w[j] = att_s[col];
            ad_w[j] = att_d[col];
        }
    }
    float ls[4] = {0.f, 0.f, 0.f, 0.f}, lq[4] = {0.f, 0.f, 0.f, 0.f};
#pragma unroll
    for (int i = 0; i < 4; ++i) {
#pragma unroll
        for (int r = 0; r < 4; ++r) {
            int row = n0 + wy * 64 + i * 16 + lg * 4 + r;
            float v0 = acc[i][0][r], v1 = acc[i][1][r];
            float v2 = acc[i][2][r], v3 = acc[i][3][r];
            if (row < N_NODES) {
                if (OUTF32) {
                    float* op = (float*)Out + (size_t)row * 128 + wx * 64 + lm;
                    op[0] = v0; op[16] = v1; op[32] = v2; op[48] = v3;
                } else {
                    unsigned short* op =
                        (unsigned short*)Out + (size_t)row * 128 + wx * 64 + lm;
                    op[0] = f2bf(v0); op[16] = f2bf(v1);
                    op[32] = f2bf(v2); op[48] = f2bf(v3);
                }
            }
            if (STATS) {  // padded rows contribute exact zeros (A zero-filled)
                ls[0] += v0; lq[0] += v0 * v0;
                ls[1] += v1; lq[1] += v1 * v1;
                ls[2] += v2; lq[2] += v2 * v2;
                ls[3] += v3; lq[3] += v3 * v3;
            }
            if (ATT) {
                float ps0 = v0 * as_w[0] + v1 * as_w[1];
                float ps1 = v2 * as_w[2] + v3 * as_w[3];
                float pd0 = v0 * ad_w[0] + v1 * ad_w[1];
                float pd1 = v2 * ad_w[2] + v3 * ad_w[3];
#pragma unroll
                for (int m = 1; m < 16; m <<= 1) {
                    ps0 += __shfl_xor(ps0, m); ps1 += __shfl_xor(ps1, m);
                    pd0 += __shfl_xor(pd0, m); pd1 += __shfl_xor(pd1, m);
                }
                if (lm == 0 && row < N_NODES) {
                    *(float2*)&a_src[row * 4 + wx * 2] = make_float2(ps0, ps1);
                    *(float2*)&a_dst[row * 4 + wx * 2] = make_float2(pd0, pd1);
                }
            }
        }
    }
    if (STATS) {
#pragma unroll
        for (int j = 0; j < 4; ++j) {
            float s = ls[j], q = lq[j];
            s += __shfl_xor(s, 16); s += __shfl_xor(s, 32);
            q += __shfl_xor(q, 16); q += __shfl_xor(q, 32);
            if (lg == 0) {
                int col = wx * 64 + j * 16 + lm;
                atomicAdd(&bnst[col], s);
                atomicAdd(&bnst[128 + col], q);
            }
        }
    }
}

// ---------------- CSR build ----------------
// Partition with LDS-staged counting sort: block-local hist -> scan -> LDS
// scatter -> COALESCED run-per-bucket global writes (avg ~10 consecutive dwords
// per bucket per block vs previous 4B random scatter: kills partial-line
// write amplification). Counts accumulate in zero-init gcursor.
__global__ __launch_bounds__(256) void k_partition(const int* __restrict__ ei,
                                                   int* __restrict__ gcursor,
                                                   int* __restrict__ staging) {
    __shared__ int hist[NBUCK];
    __shared__ int loff[NBUCK];
    __shared__ int gbase[NBUCK];
    __shared__ int lstage[PART_E];
    __shared__ int gaddr[PART_E];
    __shared__ int scanbuf[512];
    int t = threadIdx.x;
    int e0 = blockIdx.x * PART_E;
    int cntAll = min(PART_E, N_EDGES - e0);
    for (int i = t; i < NBUCK; i += 256) hist[i] = 0;
    __syncthreads();
    int pk[16];
    short bb[16], rr[16];
#pragma unroll
    for (int u = 0; u < 16; ++u) {
        int e = e0 + u * 256 + t;
        bb[u] = -1;
        rr[u] = 0;
        if (e < N_EDGES) {
            int s = ei[e], d = ei[N_EDGES + e];
            int b = d >> 8;
            int r = atomicAdd(&hist[b], 1);
            pk[u] = ((d & 255) << 17) | s;
            bb[u] = (short)b;
            rr[u] = (short)r;
        }
    }
    __syncthreads();
    // inclusive scan of hist (padded to 512), 2 elems/thread, double-read style
    scanbuf[t] = (t < NBUCK) ? hist[t] : 0;
    scanbuf[t + 256] = (t + 256 < NBUCK) ? hist[t + 256] : 0;
    __syncthreads();
    for (int off = 1; off < 512; off <<= 1) {
        int a0 = scanbuf[t];
        int a1 = scanbuf[t + 256];
        int b0 = (t >= off) ? scanbuf[t - off] : 0;
        int b1 = (t + 256 >= off) ? scanbuf[t + 256 - off] : 0;
        __syncthreads();
        scanbuf[t] = a0 + b0;
        scanbuf[t + 256] = a1 + b1;
        __syncthreads();
    }
    for (int i = t; i < NBUCK; i += 256) {
        loff[i] = scanbuf[i] - hist[i];
        gbase[i] = hist[i] ? atomicAdd(&gcursor[i], hist[i]) : 0;
    }
    __syncthreads();
#pragma unroll
    for (int u = 0; u < 16; ++u) {
        if (bb[u] >= 0) {
            int b = bb[u], r = rr[u];
            int pos = loff[b] + r;
            lstage[pos] = pk[u];
            gaddr[pos] = b * BPAD + gbase[b] + r;
        }
    }
    __syncthreads();
    for (int i = t; i < cntAll; i += 256) staging[gaddr[i]] = lstage[i];
}

// Single-atomic-pass bucket sort; each block computes its own bucket base
// (prefix over the 391 counts, L2-resident) -- scan kernel eliminated.
__global__ __launch_bounds__(256) void k_bucket_sort(const int* __restrict__ staging,
                                                     const int* __restrict__ cnts,
                                                     int* __restrict__ row_ptr,
                                                     int* __restrict__ sorted_src) {
    __shared__ int hist[256];
    __shared__ int sh[256];
    __shared__ int spill[256][2];
    __shared__ int spill_cnt;
    __shared__ int obs[4];
    int t = threadIdx.x, b = blockIdx.x;
    int part = 0;
    for (int i = t; i < b; i += 256) part += cnts[i];
#pragma unroll
    for (int m = 1; m < 64; m <<= 1) part += __shfl_xor(part, m);
    if ((t & 63) == 0) obs[t >> 6] = part;
    int cnt = cnts[b];
    hist[t] = 0;
    if (t == 0) spill_cnt = 0;
    __syncthreads();
    int ob = obs[0] + obs[1] + obs[2] + obs[3];
    const int* sb = staging + b * BPAD;
    int ent[18], rnk[18];
#pragma unroll
    for (int u = 0; u < 18; ++u) {
        int i = u * 256 + t;
        ent[u] = -1;
        rnk[u] = 0;
        if (i < cnt) {
            int p = sb[i];
            ent[u] = p;
            rnk[u] = atomicAdd(&hist[p >> 17], 1);
        }
    }
    for (int i = 18 * 256 + t; i < cnt; i += 256) {
        int p = sb[i];
        int r = atomicAdd(&hist[p >> 17], 1);
        int si = atomicAdd(&spill_cnt, 1);
        spill[si][0] = p;
        spill[si][1] = r;
    }
    __syncthreads();
    int v0 = hist[t];
    int val = v0;
    sh[t] = val;
    __syncthreads();
    for (int off = 1; off < 256; off <<= 1) {
        int o = (t >= off) ? sh[t - off] : 0;
        __syncthreads();
        val += o;
        sh[t] = val;
        __syncthreads();
    }
    int excl = val - v0;
    int d = b * 256 + t;
    if (d < N_NODES) row_ptr[d] = ob + excl;
    __syncthreads();
    hist[t] = excl;
    __syncthreads();
#pragma unroll
    for (int u = 0; u < 18; ++u) {
        if (ent[u] >= 0) {
            int p = ent[u];
            sorted_src[ob + hist[p >> 17] + rnk[u]] = p & 0x1FFFF;
        }
    }
    for (int i = t; i < spill_cnt; i += 256) {
        int p = spill[i][0];
        sorted_src[ob + hist[p >> 17] + spill[i][1]] = p & 0x1FFFF;
    }
}

// ---------------- GAT aggregate: lane-per-dword (2 channels), readlane-scalarized ----
// At the random-gather fabric ceiling (3.6 TB/s, FETCH == compulsory) -- frozen.
__global__ __launch_bounds__(256) void k_gat_agg(const uint32* __restrict__ h32,
                                                 const float* __restrict__ a_src,
                                                 const float* __restrict__ a_dst,
                                                 const int* __restrict__ row_ptr,
                                                 const int* __restrict__ sorted_src,
                                                 uint32* __restrict__ out1) {
    __shared__ alignas(16) float wbuf[4][4][72];   // [wave][head][edge]
    int lane = threadIdx.x & 63, wv = threadIdx.x >> 6;
    int hd = lane >> 4;
    int node = blockIdx.x * 4 + wv;
    int start = row_ptr[node];
    int deg = row_ptr[node + 1] - start;
    if (deg == 0) {
        out1[((uint32)node << 6) + lane] = 0u;
        return;
    }
    float4 ad = *(const float4*)&a_dst[node * 4];
    float acc0 = 0.f, acc1 = 0.f, den = 0.f;
    for (int j0 = 0; j0 < deg; j0 += 64) {
        int m = min(64, deg - j0);
        int s = 0;
        float4 w = make_float4(0.f, 0.f, 0.f, 0.f);
        if (lane < m) {
            s = sorted_src[start + j0 + lane];
            float4 as = *(const float4*)&a_src[s * 4];
            w.x = __expf(lrelu(as.x + ad.x));
            w.y = __expf(lrelu(as.y + ad.y));
            w.z = __expf(lrelu(as.z + ad.z));
            w.w = __expf(lrelu(as.w + ad.w));
        }
        wbuf[wv][0][lane] = w.x;
        wbuf[wv][1][lane] = w.y;
        wbuf[wv][2][lane] = w.z;
        wbuf[wv][3][lane] = w.w;
        __builtin_amdgcn_wave_barrier();
        int e0 = 0;
        for (; e0 + 8 <= m; e0 += 8) {
            uint32 hr[8];
#pragma unroll
            for (int k = 0; k < 8; ++k) {
                int ss = __builtin_amdgcn_readlane(s, e0 + k);
                hr[k] = h32[((uint32)ss << 6) + lane];
            }
            float4 w0 = *(const float4*)&wbuf[wv][hd][e0];
            float4 w1 = *(const float4*)&wbuf[wv][hd][e0 + 4];
            float wk[8] = {w0.x, w0.y, w0.z, w0.w, w1.x, w1.y, w1.z, w1.w};
#pragma unroll
            for (int k = 0; k < 8; ++k) {
                den += wk[k];
                acc0 = fmaf(wk[k], bflo(hr[k]), acc0);
                acc1 = fmaf(wk[k], bfhi(hr[k]), acc1);
            }
        }
        for (; e0 < m; ++e0) {
            int ss = __builtin_amdgcn_readlane(s, e0);
            uint32 hv = h32[((uint32)ss << 6) + lane];
            float wk = wbuf[wv][hd][e0];
            den += wk;
            acc0 = fmaf(wk, bflo(hv), acc0);
            acc1 = fmaf(wk, bfhi(hv), acc1);
        }
        __builtin_amdgcn_wave_barrier();
    }
    float rden = 1.f / den;
    out1[((uint32)node << 6) + lane] = packbf(acc0 * rden, acc1 * rden);
}

// ---------------- GIN aggregate with fused BN1+ELU on gathered rows --------------
// o1b stays RAW; per-lane BN scale/shift (2 channels) live in registers and are
// applied to every gathered dword + own row. Kills the bn_elu_b16 pass entirely.
__global__ __launch_bounds__(256) void k_gin_agg(const uint32* __restrict__ ob,
                                                 const int* __restrict__ row_ptr,
                                                 const int* __restrict__ sorted_src,
                                                 const float* __restrict__ eps_ptr,
                                                 const float* __restrict__ acc_,
                                                 const float* __restrict__ gamma,
                                                 const float* __restrict__ beta,
                                                 uint32* __restrict__ zb) {
    int lane = threadIdx.x & 63, wv = threadIdx.x >> 6;
    int c0 = lane * 2;
    float mu0 = acc_[c0] * (1.f / N_NODES), mu1 = acc_[c0 + 1] * (1.f / N_NODES);
    float va0 = acc_[128 + c0] * (1.f / N_NODES) - mu0 * mu0;
    float va1 = acc_[128 + c0 + 1] * (1.f / N_NODES) - mu1 * mu1;
    float s0 = rsqrtf(va0 + BN_EPS) * gamma[c0];
    float s1 = rsqrtf(va1 + BN_EPS) * gamma[c0 + 1];
    float h0 = beta[c0] - mu0 * s0;
    float h1 = beta[c0 + 1] - mu1 * s1;
    int node = blockIdx.x * 4 + wv;
    int start = row_ptr[node];
    int deg = row_ptr[node + 1] - start;
    float acc0 = 0.f, acc1 = 0.f;
    for (int j0 = 0; j0 < deg; j0 += 64) {
        int m = min(64, deg - j0);
        int s = 0;
        if (lane < m) s = sorted_src[start + j0 + lane];
        int e0 = 0;
        for (; e0 + 8 <= m; e0 += 8) {
            uint32 hr[8];
#pragma unroll
            for (int k = 0; k < 8; ++k) {
                int ss = __builtin_amdgcn_readlane(s, e0 + k);
                hr[k] = ob[((uint32)ss << 6) + lane];
            }
#pragma unroll
            for (int k = 0; k < 8; ++k) {
                float f0 = fmaf(bflo(hr[k]), s0, h0);
                float f1 = fmaf(bfhi(hr[k]), s1, h1);
                acc0 += f0 > 0.f ? f0 : __expf(f0) - 1.f;
                acc1 += f1 > 0.f ? f1 : __expf(f1) - 1.f;
            }
        }
        for (; e0 < m; ++e0) {
            int ss = __builtin_amdgcn_readlane(s, e0);
            uint32 hv = ob[((uint32)ss << 6) + lane];
            float f0 = fmaf(bflo(hv), s0, h0);
            float f1 = fmaf(bfhi(hv), s1, h1);
            acc0 += f0 > 0.f ? f0 : __expf(f0) - 1.f;
            acc1 += f1 > 0.f ? f1 : __expf(f1) - 1.f;
        }
    }
    float ep = 1.f + eps_ptr[0];
    uint32 own = ob[((uint32)node << 6) + lane];
    float f0 = fmaf(bflo(own), s0, h0);
    float f1 = fmaf(bfhi(own), s1, h1);
    f0 = f0 > 0.f ? f0 : __expf(f0) - 1.f;
    f1 = f1 > 0.f ? f1 : __expf(f1) - 1.f;
    zb[((uint32)node << 6) + lane] = packbf(fmaf(ep, f0, acc0), fmaf(ep, f1, acc1));
}

// ---------------- BN stats (bf16 input) ----------------
__global__ __launch_bounds__(256) void k_bnstats_bf16(const uint32* __restrict__ buf,
                                                      float* __restrict__ acc) {
    __shared__ float sh[4][64][4];
    int lane = threadIdx.x & 63, grp = threadIdx.x >> 6;
    float s0 = 0.f, s1 = 0.f, q0 = 0.f, q1 = 0.f;
    for (int r = blockIdx.x * 4 + grp; r < N_NODES; r += gridDim.x * 4) {
        uint32 v = buf[(size_t)r * 64 + lane];
        float v0 = bflo(v), v1 = bfhi(v);
        s0 += v0; s1 += v1; q0 += v0 * v0; q1 += v1 * v1;
    }
    sh[grp][lane][0] = s0; sh[grp][lane][1] = s1;
    sh[grp][lane][2] = q0; sh[grp][lane][3] = q1;
    __syncthreads();
    if (grp == 0) {
#pragma unroll
        for (int g = 1; g < 4; ++g) {
            s0 += sh[g][lane][0]; s1 += sh[g][lane][1];
            q0 += sh[g][lane][2]; q1 += sh[g][lane][3];
        }
        int c0 = lane * 2;
        atomicAdd(&acc[c0], s0);
        atomicAdd(&acc[c0 + 1], s1);
        atomicAdd(&acc[128 + c0], q0);
        atomicAdd(&acc[128 + c0 + 1], q1);
    }
}

// ---------------- BN + ELU: bf16 in -> fp32 out (grid-stride, register params) ------
__global__ __launch_bounds__(256) void k_bn_elu_out(const uint32* __restrict__ in,
                                                    const float* __restrict__ acc,
                                                    const float* __restrict__ gamma,
                                                    const float* __restrict__ beta,
                                                    float2* __restrict__ out) {
    int t = threadIdx.x;
    int c0 = (t & 63) * 2;
    float mu0 = acc[c0] * (1.f / N_NODES), mu1 = acc[c0 + 1] * (1.f / N_NODES);
    float va0 = acc[128 + c0] * (1.f / N_NODES) - mu0 * mu0;
    float va1 = acc[128 + c0 + 1] * (1.f / N_NODES) - mu1 * mu1;
    float s0 = rsqrtf(va0 + BN_EPS) * gamma[c0];
    float s1 = rsqrtf(va1 + BN_EPS) * gamma[c0 + 1];
    float h0 = beta[c0] - mu0 * s0;
    float h1 = beta[c0 + 1] - mu1 * s1;
    for (size_t i = (size_t)blockIdx.x * 256 + t; i < (size_t)N_NODES * 64;
         i += (size_t)ELEM_BLOCKS * 256) {
        uint32 v = in[i];
        float r0 = fmaf(bflo(v), s0, h0);
        float r1 = fmaf(bfhi(v), s1, h1);
        r0 = r0 > 0.f ? r0 : __expf(r0) - 1.f;
        r1 = r1 > 0.f ? r1 : __expf(r1) - 1.f;
        out[i] = make_float2(r0, r1);
    }
}

extern "C" void kernel_launch(void* const* d_in, const int* in_sizes, int n_in,
                              void* d_out, int out_size, void* d_ws, size_t ws_size,
                              hipStream_t stream) {
    (void)in_sizes; (void)n_in; (void)out_size; (void)ws_size;
    const float* x       = (const float*)d_in[0];
    const float* W_gat   = (const float*)d_in[1];
    const float* att_src = (const float*)d_in[2];
    const float* att_dst = (const float*)d_in[3];
    // bias_gat / lin_b cancel exactly under batch-norm -> dropped
    const float* bn1_g   = (const float*)d_in[5];
    const float* bn1_b   = (const float*)d_in[6];
    const float* eps_gin = (const float*)d_in[7];
    const float* lin_W   = (const float*)d_in[8];
    const float* bn2_g   = (const float*)d_in[10];
    const float* bn2_b   = (const float*)d_in[11];
    const int*   ei      = (const int*)d_in[12];
    float* out = (float*)d_out;

    char* w = (char*)d_ws;
    size_t o = 0;
    auto take = [&](size_t b) -> char* {
        char* p = w + o;
        o += (b + 255) & ~(size_t)255;
        return p;
    };
    unsigned short* hb   = (unsigned short*)take((size_t)N_NODES * 128 * 2);
    unsigned short* Wt1  = (unsigned short*)take((size_t)128 * IN_C * 2);
    unsigned short* Wt2  = (unsigned short*)take((size_t)128 * HID * 2);
    uint32* o1b          = (uint32*)take((size_t)N_NODES * 64 * 4);
    float* a_src         = (float*)take((size_t)N_NODES * 4 * 4);
    float* a_dst         = (float*)take((size_t)N_NODES * 4 * 4);
    int*   sorted        = (int*)take((size_t)N_EDGES * 4);
    int*   staging       = (int*)take((size_t)NBUCK * BPAD * 4);
    int*   row_ptr       = (int*)take((size_t)(N_NODES + 1) * 4);
    int*   gcursor       = (int*)take((NBUCK + 1) * 4);
    float* bnacc         = (float*)take(512 * 4);
    uint32* zb  = (uint32*)hb;  // reuse: hb dead after k_gat_agg
    uint32* o2b = o1b;          // reuse: o1b dead after k_gin_agg reads it
    const int nGemmBlocks = (N_NODES + 127) / 128;

    k_transpose_all<<<((IN_C + HID) * 128 + 255) / 256, 256, 0, stream>>>(
        W_gat, lin_W, Wt1, Wt2, gcursor, bnacc, row_ptr);
    k_gemm<true, false, true, false><<<nGemmBlocks, 256, 0, stream>>>(
        x, Wt1, hb, IN_C, att_src, att_dst, a_src, a_dst, nullptr);
    k_partition<<<NPART, 256, 0, stream>>>(ei, gcursor, staging);
    k_bucket_sort<<<NBUCK, 256, 0, stream>>>(staging, gcursor, row_ptr, sorted);
    k_gat_agg<<<N_NODES / 4, 256, 0, stream>>>((const uint32*)hb, a_src, a_dst, row_ptr,
                                               sorted, o1b);
    k_bnstats_bf16<<<512, 256, 0, stream>>>(o1b, bnacc);
    k_gin_agg<<<N_NODES / 4, 256, 0, stream>>>(o1b, row_ptr, sorted, eps_gin, bnacc,
                                               bn1_g, bn1_b, zb);
    k_gemm<false, false, false, true><<<nGemmBlocks, 256, 0, stream>>>(
        zb, Wt2, o2b, HID, nullptr, nullptr, nullptr, nullptr, bnacc + 256);
    k_bn_elu_out<<<ELEM_BLOCKS, 256, 0, stream>>>(o2b, bnacc + 256, bn2_g, bn2_b,
                                                  (float2*)out);
}

// Round 7
// 482.721 us; speedup vs baseline: 1.0379x; 1.0379x over previous
//
#include <hip/hip_runtime.h>

#define N_NODES 100000
#define N_EDGES 1600000
#define IN_C 256
#define HID 128
#define NEG_SLOPE 0.2f
#define BN_EPS 1e-5f
#define NBUCK 391          // ceil(N_NODES/256): bucket b covers dst [b*256,(b+1)*256)
#define NPART 391          // ceil(N_EDGES/4096) partition tiles
#define PART_E 4096        // edges per partition block
#define BPAD 5120          // padded per-bucket staging stride (mean 4096 + 16 sigma)
#define TBLOCKS 192        // transpose blocks: (IN_C+HID)*128/256
#define ELEM_BLOCKS 2048   // grid-stride blocks for elementwise BN kernels

typedef unsigned int uint32;
typedef __attribute__((ext_vector_type(8))) short bf16x8;
typedef __attribute__((ext_vector_type(4))) float f32x4;

__device__ __forceinline__ float lrelu(float x) { return x > 0.f ? x : NEG_SLOPE * x; }

__device__ __forceinline__ unsigned short f2bf(float f) {
    uint32 u = __float_as_uint(f);
    u += 0x7fffu + ((u >> 16) & 1u);
    return (unsigned short)(u >> 16);
}
__device__ __forceinline__ float bf2f(unsigned short h) {
    return __uint_as_float(((uint32)h) << 16);
}
__device__ __forceinline__ float bflo(uint32 v) { return __uint_as_float(v << 16); }
__device__ __forceinline__ float bfhi(uint32 v) { return __uint_as_float(v & 0xffff0000u); }
__device__ __forceinline__ uint32 packbf(float a, float b) {
    return (uint32)f2bf(a) | ((uint32)f2bf(b) << 16);
}

// ================= GEMM device body (shared by merged kernel and k_gemm2) =========
// ATT:   fuse GAT attention coefficient dot-products into the epilogue.
// STATS: fuse BN column stats (sum, sumsq) into the epilogue.
template <bool AF32, bool OUTF32, bool ATT, bool STATS>
__device__ __forceinline__ void gemm_dev(int bid, const void* __restrict__ Av,
                                         const unsigned short* __restrict__ Wt,
                                         void* __restrict__ Out, int K,
                                         const float* __restrict__ att_s,
                                         const float* __restrict__ att_d,
                                         float* __restrict__ a_src,
                                         float* __restrict__ a_dst,
                                         float* __restrict__ bnst) {
    __shared__ unsigned short As[128 * 72];
    __shared__ unsigned short Bs[128 * 72];
    const int t = threadIdx.x;
    const int n0 = bid * 128;
    const int wv = t >> 6, lane = t & 63;
    const int wy = wv >> 1, wx = wv & 1;
    const int lm = lane & 15, lg = lane >> 4;
    const float* Af = (const float*)Av;
    const unsigned short* Ah = (const unsigned short*)Av;

    f32x4 acc[4][4];
#pragma unroll
    for (int i = 0; i < 4; ++i)
#pragma unroll
        for (int j = 0; j < 4; ++j) acc[i][j] = (f32x4){0.f, 0.f, 0.f, 0.f};

    float4 afp[8];
    uint4 ahp[4];
    uint4 bvp[4];

    if (AF32) {
#pragma unroll
        for (int p = 0; p < 8; ++p) {
            int idx = p * 256 + t, row = idx >> 4, c4 = idx & 15, gn = n0 + row;
            afp[p] = (gn < N_NODES) ? *(const float4*)&Af[(size_t)gn * K + c4 * 4]
                                    : make_float4(0.f, 0.f, 0.f, 0.f);
        }
    } else {
#pragma unroll
        for (int p = 0; p < 4; ++p) {
            int idx = p * 256 + t, row = idx >> 3, c = idx & 7, gn = n0 + row;
            ahp[p] = (gn < N_NODES) ? *(const uint4*)&Ah[(size_t)gn * K + c * 8]
                                    : make_uint4(0, 0, 0, 0);
        }
    }
#pragma unroll
    for (int p = 0; p < 4; ++p) {
        int idx = p * 256 + t, n = idx >> 3, c = idx & 7;
        bvp[p] = *(const uint4*)&Wt[(size_t)n * K + c * 8];
    }

    for (int kc = 0; kc < K; kc += 64) {
        if (AF32) {
#pragma unroll
            for (int p = 0; p < 8; ++p) {
                int idx = p * 256 + t, row = idx >> 4, c4 = idx & 15;
                ushort4 b;
                b.x = f2bf(afp[p].x); b.y = f2bf(afp[p].y);
                b.z = f2bf(afp[p].z); b.w = f2bf(afp[p].w);
                *(ushort4*)&As[row * 72 + c4 * 4] = b;
            }
        } else {
#pragma unroll
            for (int p = 0; p < 4; ++p) {
                int idx = p * 256 + t, row = idx >> 3, c = idx & 7;
                *(uint4*)&As[row * 72 + c * 8] = ahp[p];
            }
        }
#pragma unroll
        for (int p = 0; p < 4; ++p) {
            int idx = p * 256 + t, n = idx >> 3, c = idx & 7;
            *(uint4*)&Bs[n * 72 + c * 8] = bvp[p];
        }
        __syncthreads();
        int kn = kc + 64;
        if (kn < K) {
            if (AF32) {
#pragma unroll
                for (int p = 0; p < 8; ++p) {
                    int idx = p * 256 + t, row = idx >> 4, c4 = idx & 15, gn = n0 + row;
                    afp[p] = (gn < N_NODES) ? *(const float4*)&Af[(size_t)gn * K + kn + c4 * 4]
                                            : make_float4(0.f, 0.f, 0.f, 0.f);
                }
            } else {
#pragma unroll
                for (int p = 0; p < 4; ++p) {
                    int idx = p * 256 + t, row = idx >> 3, c = idx & 7, gn = n0 + row;
                    ahp[p] = (gn < N_NODES) ? *(const uint4*)&Ah[(size_t)gn * K + kn + c * 8]
                                            : make_uint4(0, 0, 0, 0);
                }
            }
#pragma unroll
            for (int p = 0; p < 4; ++p) {
                int idx = p * 256 + t, n = idx >> 3, c = idx & 7;
                bvp[p] = *(const uint4*)&Wt[(size_t)n * K + kn + c * 8];
            }
        }
#pragma unroll
        for (int ks = 0; ks < 2; ++ks) {
            bf16x8 af[4], bfr[4];
#pragma unroll
            for (int i = 0; i < 4; ++i)
                af[i] = *(const bf16x8*)&As[(wy * 64 + i * 16 + lm) * 72 + ks * 32 + lg * 8];
#pragma unroll
            for (int j = 0; j < 4; ++j)
                bfr[j] = *(const bf16x8*)&Bs[(wx * 64 + j * 16 + lm) * 72 + ks * 32 + lg * 8];
#pragma unroll
            for (int i = 0; i < 4; ++i)
#pragma unroll
                for (int j = 0; j < 4; ++j)
                    acc[i][j] = __builtin_amdgcn_mfma_f32_16x16x32_bf16(af[i], bfr[j],
                                                                        acc[i][j], 0, 0, 0);
        }
        __syncthreads();
    }

    // ---- epilogue ----
    float as_w[4], ad_w[4];
    if (ATT) {
#pragma unroll
        for (int j = 0; j < 4; ++j) {
            int col = wx * 64 + j * 16 + lm;
            as_w[j] = att_s[col];
            ad_w[j] = att_d[col];
        }
    }
    float ls[4] = {0.f, 0.f, 0.f, 0.f}, lq[4] = {0.f, 0.f, 0.f, 0.f};
#pragma unroll
    for (int i = 0; i < 4; ++i) {
#pragma unroll
        for (int r = 0; r < 4; ++r) {
            int row = n0 + wy * 64 + i * 16 + lg * 4 + r;
            float v0 = acc[i][0][r], v1 = acc[i][1][r];
            float v2 = acc[i][2][r], v3 = acc[i][3][r];
            if (row < N_NODES) {
                if (OUTF32) {
                    float* op = (float*)Out + (size_t)row * 128 + wx * 64 + lm;
                    op[0] = v0; op[16] = v1; op[32] = v2; op[48] = v3;
                } else {
                    unsigned short* op =
                        (unsigned short*)Out + (size_t)row * 128 + wx * 64 + lm;
                    op[0] = f2bf(v0); op[16] = f2bf(v1);
                    op[32] = f2bf(v2); op[48] = f2bf(v3);
                }
            }
            if (STATS) {  // padded rows contribute exact zeros (A zero-filled)
                ls[0] += v0; lq[0] += v0 * v0;
                ls[1] += v1; lq[1] += v1 * v1;
                ls[2] += v2; lq[2] += v2 * v2;
                ls[3] += v3; lq[3] += v3 * v3;
            }
            if (ATT) {
                float ps0 = v0 * as_w[0] + v1 * as_w[1];
                float ps1 = v2 * as_w[2] + v3 * as_w[3];
                float pd0 = v0 * ad_w[0] + v1 * ad_w[1];
                float pd1 = v2 * ad_w[2] + v3 * ad_w[3];
#pragma unroll
                for (int m = 1; m < 16; m <<= 1) {
                    ps0 += __shfl_xor(ps0, m); ps1 += __shfl_xor(ps1, m);
                    pd0 += __shfl_xor(pd0, m); pd1 += __shfl_xor(pd1, m);
                }
                if (lm == 0 && row < N_NODES) {
                    *(float2*)&a_src[row * 4 + wx * 2] = make_float2(ps0, ps1);
                    *(float2*)&a_dst[row * 4 + wx * 2] = make_float2(pd0, pd1);
                }
            }
        }
    }
    if (STATS) {
#pragma unroll
        for (int j = 0; j < 4; ++j) {
            float s = ls[j], q = lq[j];
            s += __shfl_xor(s, 16); s += __shfl_xor(s, 32);
            q += __shfl_xor(q, 16); q += __shfl_xor(q, 32);
            if (lg == 0) {
                int col = wx * 64 + j * 16 + lm;
                atomicAdd(&bnst[col], s);
                atomicAdd(&bnst[128 + col], q);
            }
        }
    }
}

// ================= bucket_sort device body ========================================
// Single-atomic-pass; block computes own bucket base (prefix over L2-resident counts).
__device__ __forceinline__ void bucket_sort_dev(int b, const int* __restrict__ staging,
                                                const int* __restrict__ cnts,
                                                int* __restrict__ row_ptr,
                                                int* __restrict__ sorted_src) {
    __shared__ int hist[256];
    __shared__ int sh[256];
    __shared__ int spill[256][2];
    __shared__ int spill_cnt;
    __shared__ int obs[4];
    int t = threadIdx.x;
    int part = 0;
    for (int i = t; i < b; i += 256) part += cnts[i];
#pragma unroll
    for (int m = 1; m < 64; m <<= 1) part += __shfl_xor(part, m);
    if ((t & 63) == 0) obs[t >> 6] = part;
    int cnt = cnts[b];
    hist[t] = 0;
    if (t == 0) spill_cnt = 0;
    __syncthreads();
    int ob = obs[0] + obs[1] + obs[2] + obs[3];
    const int* sb = staging + b * BPAD;
    int ent[18], rnk[18];
#pragma unroll
    for (int u = 0; u < 18; ++u) {
        int i = u * 256 + t;
        ent[u] = -1;
        rnk[u] = 0;
        if (i < cnt) {
            int p = sb[i];
            ent[u] = p;
            rnk[u] = atomicAdd(&hist[p >> 17], 1);
        }
    }
    for (int i = 18 * 256 + t; i < cnt; i += 256) {
        int p = sb[i];
        int r = atomicAdd(&hist[p >> 17], 1);
        int si = atomicAdd(&spill_cnt, 1);
        spill[si][0] = p;
        spill[si][1] = r;
    }
    __syncthreads();
    int v0 = hist[t];
    int val = v0;
    sh[t] = val;
    __syncthreads();
    for (int off = 1; off < 256; off <<= 1) {
        int o = (t >= off) ? sh[t - off] : 0;
        __syncthreads();
        val += o;
        sh[t] = val;
        __syncthreads();
    }
    int excl = val - v0;
    int d = b * 256 + t;
    if (d < N_NODES) row_ptr[d] = ob + excl;
    __syncthreads();
    hist[t] = excl;
    __syncthreads();
#pragma unroll
    for (int u = 0; u < 18; ++u) {
        if (ent[u] >= 0) {
            int p = ent[u];
            sorted_src[ob + hist[p >> 17] + rnk[u]] = p & 0x1FFFF;
        }
    }
    for (int i = t; i < spill_cnt; i += 256) {
        int p = spill[i][0];
        sorted_src[ob + hist[p >> 17] + spill[i][1]] = p & 0x1FFFF;
    }
}

// ================= launch 1: partition (blocks 0..NPART-1) + transpose/init rest ==
// Partition: LDS counting sort -> coalesced per-bucket runs (kills partial-line
// write amplification). gcursor pre-zeroed by hipMemsetAsync (race-free).
// Transpose region also zeroes bnacc and sets row_ptr[N] (no consumer until launch 3+).
__global__ __launch_bounds__(256) void k_prep(const int* __restrict__ ei,
                                              int* __restrict__ gcursor,
                                              int* __restrict__ staging,
                                              const float* __restrict__ W1,
                                              const float* __restrict__ W2,
                                              unsigned short* __restrict__ Wt1,
                                              unsigned short* __restrict__ Wt2,
                                              float* __restrict__ bnacc,
                                              int* __restrict__ row_ptr) {
    int t = threadIdx.x;
    if (blockIdx.x >= NPART) {
        int tb = blockIdx.x - NPART;
        if (tb == 0) {
            bnacc[t] = 0.f;
            bnacc[256 + t] = 0.f;
            if (t == 0) row_ptr[N_NODES] = N_EDGES;
        }
        int idx = tb * 256 + t;
        if (idx < IN_C * 128) {
            int k = idx >> 7, n = idx & 127;
            Wt1[n * IN_C + k] = f2bf(W1[idx]);
        } else {
            idx -= IN_C * 128;
            if (idx < HID * 128) {
                int k = idx >> 7, n = idx & 127;
                Wt2[n * HID + k] = f2bf(W2[idx]);
            }
        }
        return;
    }
    __shared__ int hist[NBUCK];
    __shared__ int loff[NBUCK];
    __shared__ int gbase[NBUCK];
    __shared__ int lstage[PART_E];
    __shared__ int gaddr[PART_E];
    __shared__ int scanbuf[512];
    int e0 = blockIdx.x * PART_E;
    int cntAll = min(PART_E, N_EDGES - e0);
    for (int i = t; i < NBUCK; i += 256) hist[i] = 0;
    __syncthreads();
    int pk[16];
    short bb[16], rr[16];
#pragma unroll
    for (int u = 0; u < 16; ++u) {
        int e = e0 + u * 256 + t;
        bb[u] = -1;
        rr[u] = 0;
        if (e < N_EDGES) {
            int s = ei[e], d = ei[N_EDGES + e];
            int b = d >> 8;
            int r = atomicAdd(&hist[b], 1);
            pk[u] = ((d & 255) << 17) | s;
            bb[u] = (short)b;
            rr[u] = (short)r;
        }
    }
    __syncthreads();
    scanbuf[t] = (t < NBUCK) ? hist[t] : 0;
    scanbuf[t + 256] = (t + 256 < NBUCK) ? hist[t + 256] : 0;
    __syncthreads();
    for (int off = 1; off < 512; off <<= 1) {
        int a0 = scanbuf[t];
        int a1 = scanbuf[t + 256];
        int b0 = (t >= off) ? scanbuf[t - off] : 0;
        int b1 = (t + 256 >= off) ? scanbuf[t + 256 - off] : 0;
        __syncthreads();
        scanbuf[t] = a0 + b0;
        scanbuf[t + 256] = a1 + b1;
        __syncthreads();
    }
    for (int i = t; i < NBUCK; i += 256) {
        loff[i] = scanbuf[i] - hist[i];
        gbase[i] = hist[i] ? atomicAdd(&gcursor[i], hist[i]) : 0;
    }
    __syncthreads();
#pragma unroll
    for (int u = 0; u < 16; ++u) {
        if (bb[u] >= 0) {
            int b = bb[u], r = rr[u];
            int pos = loff[b] + r;
            lstage[pos] = pk[u];
            gaddr[pos] = b * BPAD + gbase[b] + r;
        }
    }
    __syncthreads();
    for (int i = t; i < cntAll; i += 256) staging[gaddr[i]] = lstage[i];
}

// ================= launch 2: bucket_sort (blocks 0..NBUCK-1) || GEMM1 (rest) ======
// Independent given launch 1 -> run concurrently in one dispatch.
__global__ __launch_bounds__(256) void k_gemm1_sort(const int* __restrict__ staging,
                                                    const int* __restrict__ cnts,
                                                    int* __restrict__ row_ptr,
                                                    int* __restrict__ sorted_src,
                                                    const float* __restrict__ x,
                                                    const unsigned short* __restrict__ Wt1,
                                                    unsigned short* __restrict__ hb,
                                                    const float* __restrict__ att_s,
                                                    const float* __restrict__ att_d,
                                                    float* __restrict__ a_src,
                                                    float* __restrict__ a_dst) {
    if (blockIdx.x < NBUCK) {
        bucket_sort_dev(blockIdx.x, staging, cnts, row_ptr, sorted_src);
    } else {
        gemm_dev<true, false, true, false>(blockIdx.x - NBUCK, x, Wt1, hb, IN_C,
                                           att_s, att_d, a_src, a_dst, nullptr);
    }
}

// ================= GEMM2 standalone (fused BN2 stats) =============================
__global__ __launch_bounds__(256) void k_gemm2(const void* __restrict__ Av,
                                               const unsigned short* __restrict__ Wt,
                                               void* __restrict__ Out,
                                               float* __restrict__ bnst) {
    gemm_dev<false, false, false, true>(blockIdx.x, Av, Wt, Out, HID,
                                        nullptr, nullptr, nullptr, nullptr, bnst);
}

// ---------------- GAT aggregate: lane-per-dword (2 channels), readlane-scalarized ----
// At the random-gather fabric ceiling (3.6 TB/s, FETCH == compulsory) -- frozen.
__global__ __launch_bounds__(256) void k_gat_agg(const uint32* __restrict__ h32,
                                                 const float* __restrict__ a_src,
                                                 const float* __restrict__ a_dst,
                                                 const int* __restrict__ row_ptr,
                                                 const int* __restrict__ sorted_src,
                                                 uint32* __restrict__ out1) {
    __shared__ alignas(16) float wbuf[4][4][72];   // [wave][head][edge]
    int lane = threadIdx.x & 63, wv = threadIdx.x >> 6;
    int hd = lane >> 4;
    int node = blockIdx.x * 4 + wv;
    int start = row_ptr[node];
    int deg = row_ptr[node + 1] - start;
    if (deg == 0) {
        out1[((uint32)node << 6) + lane] = 0u;
        return;
    }
    float4 ad = *(const float4*)&a_dst[node * 4];
    float acc0 = 0.f, acc1 = 0.f, den = 0.f;
    for (int j0 = 0; j0 < deg; j0 += 64) {
        int m = min(64, deg - j0);
        int s = 0;
        float4 w = make_float4(0.f, 0.f, 0.f, 0.f);
        if (lane < m) {
            s = sorted_src[start + j0 + lane];
            float4 as = *(const float4*)&a_src[s * 4];
            w.x = __expf(lrelu(as.x + ad.x));
            w.y = __expf(lrelu(as.y + ad.y));
            w.z = __expf(lrelu(as.z + ad.z));
            w.w = __expf(lrelu(as.w + ad.w));
        }
        wbuf[wv][0][lane] = w.x;
        wbuf[wv][1][lane] = w.y;
        wbuf[wv][2][lane] = w.z;
        wbuf[wv][3][lane] = w.w;
        __builtin_amdgcn_wave_barrier();
        int e0 = 0;
        for (; e0 + 8 <= m; e0 += 8) {
            uint32 hr[8];
#pragma unroll
            for (int k = 0; k < 8; ++k) {
                int ss = __builtin_amdgcn_readlane(s, e0 + k);
                hr[k] = h32[((uint32)ss << 6) + lane];
            }
            float4 w0 = *(const float4*)&wbuf[wv][hd][e0];
            float4 w1 = *(const float4*)&wbuf[wv][hd][e0 + 4];
            float wk[8] = {w0.x, w0.y, w0.z, w0.w, w1.x, w1.y, w1.z, w1.w};
#pragma unroll
            for (int k = 0; k < 8; ++k) {
                den += wk[k];
                acc0 = fmaf(wk[k], bflo(hr[k]), acc0);
                acc1 = fmaf(wk[k], bfhi(hr[k]), acc1);
            }
        }
        for (; e0 < m; ++e0) {
            int ss = __builtin_amdgcn_readlane(s, e0);
            uint32 hv = h32[((uint32)ss << 6) + lane];
            float wk = wbuf[wv][hd][e0];
            den += wk;
            acc0 = fmaf(wk, bflo(hv), acc0);
            acc1 = fmaf(wk, bfhi(hv), acc1);
        }
        __builtin_amdgcn_wave_barrier();
    }
    float rden = 1.f / den;
    out1[((uint32)node << 6) + lane] = packbf(acc0 * rden, acc1 * rden);
}

// ---------------- GIN aggregate with fused BN1+ELU on gathered rows --------------
__global__ __launch_bounds__(256) void k_gin_agg(const uint32* __restrict__ ob,
                                                 const int* __restrict__ row_ptr,
                                                 const int* __restrict__ sorted_src,
                                                 const float* __restrict__ eps_ptr,
                                                 const float* __restrict__ acc_,
                                                 const float* __restrict__ gamma,
                                                 const float* __restrict__ beta,
                                                 uint32* __restrict__ zb) {
    int lane = threadIdx.x & 63, wv = threadIdx.x >> 6;
    int c0 = lane * 2;
    float mu0 = acc_[c0] * (1.f / N_NODES), mu1 = acc_[c0 + 1] * (1.f / N_NODES);
    float va0 = acc_[128 + c0] * (1.f / N_NODES) - mu0 * mu0;
    float va1 = acc_[128 + c0 + 1] * (1.f / N_NODES) - mu1 * mu1;
    float s0 = rsqrtf(va0 + BN_EPS) * gamma[c0];
    float s1 = rsqrtf(va1 + BN_EPS) * gamma[c0 + 1];
    float h0 = beta[c0] - mu0 * s0;
    float h1 = beta[c0 + 1] - mu1 * s1;
    int node = blockIdx.x * 4 + wv;
    int start = row_ptr[node];
    int deg = row_ptr[node + 1] - start;
    float acc0 = 0.f, acc1 = 0.f;
    for (int j0 = 0; j0 < deg; j0 += 64) {
        int m = min(64, deg - j0);
        int s = 0;
        if (lane < m) s = sorted_src[start + j0 + lane];
        int e0 = 0;
        for (; e0 + 8 <= m; e0 += 8) {
            uint32 hr[8];
#pragma unroll
            for (int k = 0; k < 8; ++k) {
                int ss = __builtin_amdgcn_readlane(s, e0 + k);
                hr[k] = ob[((uint32)ss << 6) + lane];
            }
#pragma unroll
            for (int k = 0; k < 8; ++k) {
                float f0 = fmaf(bflo(hr[k]), s0, h0);
                float f1 = fmaf(bfhi(hr[k]), s1, h1);
                acc0 += f0 > 0.f ? f0 : __expf(f0) - 1.f;
                acc1 += f1 > 0.f ? f1 : __expf(f1) - 1.f;
            }
        }
        for (; e0 < m; ++e0) {
            int ss = __builtin_amdgcn_readlane(s, e0);
            uint32 hv = ob[((uint32)ss << 6) + lane];
            float f0 = fmaf(bflo(hv), s0, h0);
            float f1 = fmaf(bfhi(hv), s1, h1);
            acc0 += f0 > 0.f ? f0 : __expf(f0) - 1.f;
            acc1 += f1 > 0.f ? f1 : __expf(f1) - 1.f;
        }
    }
    float ep = 1.f + eps_ptr[0];
    uint32 own = ob[((uint32)node << 6) + lane];
    float f0 = fmaf(bflo(own), s0, h0);
    float f1 = fmaf(bfhi(own), s1, h1);
    f0 = f0 > 0.f ? f0 : __expf(f0) - 1.f;
    f1 = f1 > 0.f ? f1 : __expf(f1) - 1.f;
    zb[((uint32)node << 6) + lane] = packbf(fmaf(ep, f0, acc0), fmaf(ep, f1, acc1));
}

// ---------------- BN stats (bf16 input) ----------------
__global__ __launch_bounds__(256) void k_bnstats_bf16(const uint32* __restrict__ buf,
                                                      float* __restrict__ acc) {
    __shared__ float sh[4][64][4];
    int lane = threadIdx.x & 63, grp = threadIdx.x >> 6;
    float s0 = 0.f, s1 = 0.f, q0 = 0.f, q1 = 0.f;
    for (int r = blockIdx.x * 4 + grp; r < N_NODES; r += gridDim.x * 4) {
        uint32 v = buf[(size_t)r * 64 + lane];
        float v0 = bflo(v), v1 = bfhi(v);
        s0 += v0; s1 += v1; q0 += v0 * v0; q1 += v1 * v1;
    }
    sh[grp][lane][0] = s0; sh[grp][lane][1] = s1;
    sh[grp][lane][2] = q0; sh[grp][lane][3] = q1;
    __syncthreads();
    if (grp == 0) {
#pragma unroll
        for (int g = 1; g < 4; ++g) {
            s0 += sh[g][lane][0]; s1 += sh[g][lane][1];
            q0 += sh[g][lane][2]; q1 += sh[g][lane][3];
        }
        int c0 = lane * 2;
        atomicAdd(&acc[c0], s0);
        atomicAdd(&acc[c0 + 1], s1);
        atomicAdd(&acc[128 + c0], q0);
        atomicAdd(&acc[128 + c0 + 1], q1);
    }
}

// ---------------- BN + ELU: bf16 in -> fp32 out (grid-stride, register params) ------
__global__ __launch_bounds__(256) void k_bn_elu_out(const uint32* __restrict__ in,
                                                    const float* __restrict__ acc,
                                                    const float* __restrict__ gamma,
                                                    const float* __restrict__ beta,
                                                    float2* __restrict__ out) {
    int t = threadIdx.x;
    int c0 = (t & 63) * 2;
    float mu0 = acc[c0] * (1.f / N_NODES), mu1 = acc[c0 + 1] * (1.f / N_NODES);
    float va0 = acc[128 + c0] * (1.f / N_NODES) - mu0 * mu0;
    float va1 = acc[128 + c0 + 1] * (1.f / N_NODES) - mu1 * mu1;
    float s0 = rsqrtf(va0 + BN_EPS) * gamma[c0];
    float s1 = rsqrtf(va1 + BN_EPS) * gamma[c0 + 1];
    float h0 = beta[c0] - mu0 * s0;
    float h1 = beta[c0 + 1] - mu1 * s1;
    for (size_t i = (size_t)blockIdx.x * 256 + t; i < (size_t)N_NODES * 64;
         i += (size_t)ELEM_BLOCKS * 256) {
        uint32 v = in[i];
        float r0 = fmaf(bflo(v), s0, h0);
        float r1 = fmaf(bfhi(v), s1, h1);
        r0 = r0 > 0.f ? r0 : __expf(r0) - 1.f;
        r1 = r1 > 0.f ? r1 : __expf(r1) - 1.f;
        out[i] = make_float2(r0, r1);
    }
}

extern "C" void kernel_launch(void* const* d_in, const int* in_sizes, int n_in,
                              void* d_out, int out_size, void* d_ws, size_t ws_size,
                              hipStream_t stream) {
    (void)in_sizes; (void)n_in; (void)out_size; (void)ws_size;
    const float* x       = (const float*)d_in[0];
    const float* W_gat   = (const float*)d_in[1];
    const float* att_src = (const float*)d_in[2];
    const float* att_dst = (const float*)d_in[3];
    // bias_gat / lin_b cancel exactly under batch-norm -> dropped
    const float* bn1_g   = (const float*)d_in[5];
    const float* bn1_b   = (const float*)d_in[6];
    const float* eps_gin = (const float*)d_in[7];
    const float* lin_W   = (const float*)d_in[8];
    const float* bn2_g   = (const float*)d_in[10];
    const float* bn2_b   = (const float*)d_in[11];
    const int*   ei      = (const int*)d_in[12];
    float* out = (float*)d_out;

    char* w = (char*)d_ws;
    size_t o = 0;
    auto take = [&](size_t b) -> char* {
        char* p = w + o;
        o += (b + 255) & ~(size_t)255;
        return p;
    };
    unsigned short* hb   = (unsigned short*)take((size_t)N_NODES * 128 * 2);
    unsigned short* Wt1  = (unsigned short*)take((size_t)128 * IN_C * 2);
    unsigned short* Wt2  = (unsigned short*)take((size_t)128 * HID * 2);
    uint32* o1b          = (uint32*)take((size_t)N_NODES * 64 * 4);
    float* a_src         = (float*)take((size_t)N_NODES * 4 * 4);
    float* a_dst         = (float*)take((size_t)N_NODES * 4 * 4);
    int*   sorted        = (int*)take((size_t)N_EDGES * 4);
    int*   staging       = (int*)take((size_t)NBUCK * BPAD * 4);
    int*   row_ptr       = (int*)take((size_t)(N_NODES + 1) * 4);
    // gcursor + bnacc adjacent: one memset covers both
    int*   gcursor       = (int*)take((NBUCK + 1) * 4);
    float* bnacc         = (float*)take(512 * 4);
    uint32* zb  = (uint32*)hb;  // reuse: hb dead after k_gat_agg
    uint32* o2b = o1b;          // reuse: o1b dead after k_gin_agg reads it
    const int nGemmBlocks = (N_NODES + 127) / 128;

    // zero gcursor only (bnacc zeroed inside k_prep transpose region)
    hipMemsetAsync(gcursor, 0, (NBUCK + 1) * sizeof(int), stream);
    k_prep<<<NPART + TBLOCKS, 256, 0, stream>>>(ei, gcursor, staging, W_gat, lin_W,
                                                Wt1, Wt2, bnacc, row_ptr);
    k_gemm1_sort<<<NBUCK + nGemmBlocks, 256, 0, stream>>>(
        staging, gcursor, row_ptr, sorted, x, Wt1, hb, att_src, att_dst, a_src, a_dst);
    k_gat_agg<<<N_NODES / 4, 256, 0, stream>>>((const uint32*)hb, a_src, a_dst, row_ptr,
                                               sorted, o1b);
    k_bnstats_bf16<<<512, 256, 0, stream>>>(o1b, bnacc);
    k_gin_agg<<<N_NODES / 4, 256, 0, stream>>>(o1b, row_ptr, sorted, eps_gin, bnacc,
                                               bn1_g, bn1_b, zb);
    k_gemm2<<<nGemmBlocks, 256, 0, stream>>>(zb, Wt2, o2b, bnacc + 256);
    k_bn_elu_out<<<ELEM_BLOCKS, 256, 0, stream>>>(o2b, bnacc + 256, bn2_g, bn2_b,
                                                  (float2*)out);
}

// Round 8
// 479.856 us; speedup vs baseline: 1.0441x; 1.0060x over previous
//
#include <hip/hip_runtime.h>

#define N_NODES 100000
#define N_EDGES 1600000
#define IN_C 256
#define HID 128
#define NEG_SLOPE 0.2f
#define BN_EPS 1e-5f
#define NBUCK 391          // ceil(N_NODES/256): bucket b covers dst [b*256,(b+1)*256)
#define NPART 391          // ceil(N_EDGES/4096) partition tiles
#define PART_E 4096        // edges per partition block
#define BPAD 5120          // padded per-bucket staging stride (mean 4096 + 16 sigma)
#define TBLOCKS 192        // transpose blocks: (IN_C+HID)*128/256
#define NSPLIT 32          // BN1 partial-stat buffer copies (contention 25000/32)
#define ELEM_BLOCKS 2048   // grid-stride blocks for elementwise BN kernels

typedef unsigned int uint32;
typedef __attribute__((ext_vector_type(8))) short bf16x8;
typedef __attribute__((ext_vector_type(4))) float f32x4;

__device__ __forceinline__ float lrelu(float x) { return x > 0.f ? x : NEG_SLOPE * x; }

__device__ __forceinline__ unsigned short f2bf(float f) {
    uint32 u = __float_as_uint(f);
    u += 0x7fffu + ((u >> 16) & 1u);
    return (unsigned short)(u >> 16);
}
__device__ __forceinline__ float bf2f(unsigned short h) {
    return __uint_as_float(((uint32)h) << 16);
}
__device__ __forceinline__ float bflo(uint32 v) { return __uint_as_float(v << 16); }
__device__ __forceinline__ float bfhi(uint32 v) { return __uint_as_float(v & 0xffff0000u); }
__device__ __forceinline__ uint32 packbf(float a, float b) {
    return (uint32)f2bf(a) | ((uint32)f2bf(b) << 16);
}

// ================= GEMM device body (shared by merged kernel and k_gemm2) =========
// ATT:   fuse GAT attention coefficient dot-products into the epilogue.
// STATS: fuse BN column stats (sum, sumsq) into the epilogue.
template <bool AF32, bool OUTF32, bool ATT, bool STATS>
__device__ __forceinline__ void gemm_dev(int bid, const void* __restrict__ Av,
                                         const unsigned short* __restrict__ Wt,
                                         void* __restrict__ Out, int K,
                                         const float* __restrict__ att_s,
                                         const float* __restrict__ att_d,
                                         float* __restrict__ a_src,
                                         float* __restrict__ a_dst,
                                         float* __restrict__ bnst) {
    __shared__ unsigned short As[128 * 72];
    __shared__ unsigned short Bs[128 * 72];
    const int t = threadIdx.x;
    const int n0 = bid * 128;
    const int wv = t >> 6, lane = t & 63;
    const int wy = wv >> 1, wx = wv & 1;
    const int lm = lane & 15, lg = lane >> 4;
    const float* Af = (const float*)Av;
    const unsigned short* Ah = (const unsigned short*)Av;

    f32x4 acc[4][4];
#pragma unroll
    for (int i = 0; i < 4; ++i)
#pragma unroll
        for (int j = 0; j < 4; ++j) acc[i][j] = (f32x4){0.f, 0.f, 0.f, 0.f};

    float4 afp[8];
    uint4 ahp[4];
    uint4 bvp[4];

    if (AF32) {
#pragma unroll
        for (int p = 0; p < 8; ++p) {
            int idx = p * 256 + t, row = idx >> 4, c4 = idx & 15, gn = n0 + row;
            afp[p] = (gn < N_NODES) ? *(const float4*)&Af[(size_t)gn * K + c4 * 4]
                                    : make_float4(0.f, 0.f, 0.f, 0.f);
        }
    } else {
#pragma unroll
        for (int p = 0; p < 4; ++p) {
            int idx = p * 256 + t, row = idx >> 3, c = idx & 7, gn = n0 + row;
            ahp[p] = (gn < N_NODES) ? *(const uint4*)&Ah[(size_t)gn * K + c * 8]
                                    : make_uint4(0, 0, 0, 0);
        }
    }
#pragma unroll
    for (int p = 0; p < 4; ++p) {
        int idx = p * 256 + t, n = idx >> 3, c = idx & 7;
        bvp[p] = *(const uint4*)&Wt[(size_t)n * K + c * 8];
    }

    for (int kc = 0; kc < K; kc += 64) {
        if (AF32) {
#pragma unroll
            for (int p = 0; p < 8; ++p) {
                int idx = p * 256 + t, row = idx >> 4, c4 = idx & 15;
                ushort4 b;
                b.x = f2bf(afp[p].x); b.y = f2bf(afp[p].y);
                b.z = f2bf(afp[p].z); b.w = f2bf(afp[p].w);
                *(ushort4*)&As[row * 72 + c4 * 4] = b;
            }
        } else {
#pragma unroll
            for (int p = 0; p < 4; ++p) {
                int idx = p * 256 + t, row = idx >> 3, c = idx & 7;
                *(uint4*)&As[row * 72 + c * 8] = ahp[p];
            }
        }
#pragma unroll
        for (int p = 0; p < 4; ++p) {
            int idx = p * 256 + t, n = idx >> 3, c = idx & 7;
            *(uint4*)&Bs[n * 72 + c * 8] = bvp[p];
        }
        __syncthreads();
        int kn = kc + 64;
        if (kn < K) {
            if (AF32) {
#pragma unroll
                for (int p = 0; p < 8; ++p) {
                    int idx = p * 256 + t, row = idx >> 4, c4 = idx & 15, gn = n0 + row;
                    afp[p] = (gn < N_NODES) ? *(const float4*)&Af[(size_t)gn * K + kn + c4 * 4]
                                            : make_float4(0.f, 0.f, 0.f, 0.f);
                }
            } else {
#pragma unroll
                for (int p = 0; p < 4; ++p) {
                    int idx = p * 256 + t, row = idx >> 3, c = idx & 7, gn = n0 + row;
                    ahp[p] = (gn < N_NODES) ? *(const uint4*)&Ah[(size_t)gn * K + kn + c * 8]
                                            : make_uint4(0, 0, 0, 0);
                }
            }
#pragma unroll
            for (int p = 0; p < 4; ++p) {
                int idx = p * 256 + t, n = idx >> 3, c = idx & 7;
                bvp[p] = *(const uint4*)&Wt[(size_t)n * K + kn + c * 8];
            }
        }
#pragma unroll
        for (int ks = 0; ks < 2; ++ks) {
            bf16x8 af[4], bfr[4];
#pragma unroll
            for (int i = 0; i < 4; ++i)
                af[i] = *(const bf16x8*)&As[(wy * 64 + i * 16 + lm) * 72 + ks * 32 + lg * 8];
#pragma unroll
            for (int j = 0; j < 4; ++j)
                bfr[j] = *(const bf16x8*)&Bs[(wx * 64 + j * 16 + lm) * 72 + ks * 32 + lg * 8];
#pragma unroll
            for (int i = 0; i < 4; ++i)
#pragma unroll
                for (int j = 0; j < 4; ++j)
                    acc[i][j] = __builtin_amdgcn_mfma_f32_16x16x32_bf16(af[i], bfr[j],
                                                                        acc[i][j], 0, 0, 0);
        }
        __syncthreads();
    }

    // ---- epilogue ----
    float as_w[4], ad_w[4];
    if (ATT) {
#pragma unroll
        for (int j = 0; j < 4; ++j) {
            int col = wx * 64 + j * 16 + lm;
            as_w[j] = att_s[col];
            ad_w[j] = att_d[col];
        }
    }
    float ls[4] = {0.f, 0.f, 0.f, 0.f}, lq[4] = {0.f, 0.f, 0.f, 0.f};
#pragma unroll
    for (int i = 0; i < 4; ++i) {
#pragma unroll
        for (int r = 0; r < 4; ++r) {
            int row = n0 + wy * 64 + i * 16 + lg * 4 + r;
            float v0 = acc[i][0][r], v1 = acc[i][1][r];
            float v2 = acc[i][2][r], v3 = acc[i][3][r];
            if (row < N_NODES) {
                if (OUTF32) {
                    float* op = (float*)Out + (size_t)row * 128 + wx * 64 + lm;
                    op[0] = v0; op[16] = v1; op[32] = v2; op[48] = v3;
                } else {
                    unsigned short* op =
                        (unsigned short*)Out + (size_t)row * 128 + wx * 64 + lm;
                    op[0] = f2bf(v0); op[16] = f2bf(v1);
                    op[32] = f2bf(v2); op[48] = f2bf(v3);
                }
            }
            if (STATS) {  // padded rows contribute exact zeros (A zero-filled)
                ls[0] += v0; lq[0] += v0 * v0;
                ls[1] += v1; lq[1] += v1 * v1;
                ls[2] += v2; lq[2] += v2 * v2;
                ls[3] += v3; lq[3] += v3 * v3;
            }
            if (ATT) {
                float ps0 = v0 * as_w[0] + v1 * as_w[1];
                float ps1 = v2 * as_w[2] + v3 * as_w[3];
                float pd0 = v0 * ad_w[0] + v1 * ad_w[1];
                float pd1 = v2 * ad_w[2] + v3 * ad_w[3];
#pragma unroll
                for (int m = 1; m < 16; m <<= 1) {
                    ps0 += __shfl_xor(ps0, m); ps1 += __shfl_xor(ps1, m);
                    pd0 += __shfl_xor(pd0, m); pd1 += __shfl_xor(pd1, m);
                }
                if (lm == 0 && row < N_NODES) {
                    *(float2*)&a_src[row * 4 + wx * 2] = make_float2(ps0, ps1);
                    *(float2*)&a_dst[row * 4 + wx * 2] = make_float2(pd0, pd1);
                }
            }
        }
    }
    if (STATS) {
#pragma unroll
        for (int j = 0; j < 4; ++j) {
            float s = ls[j], q = lq[j];
            s += __shfl_xor(s, 16); s += __shfl_xor(s, 32);
            q += __shfl_xor(q, 16); q += __shfl_xor(q, 32);
            if (lg == 0) {
                int col = wx * 64 + j * 16 + lm;
                atomicAdd(&bnst[col], s);
                atomicAdd(&bnst[128 + col], q);
            }
        }
    }
}

// ================= bucket_sort device body ========================================
__device__ __forceinline__ void bucket_sort_dev(int b, const int* __restrict__ staging,
                                                const int* __restrict__ cnts,
                                                int* __restrict__ row_ptr,
                                                int* __restrict__ sorted_src) {
    __shared__ int hist[256];
    __shared__ int sh[256];
    __shared__ int spill[256][2];
    __shared__ int spill_cnt;
    __shared__ int obs[4];
    int t = threadIdx.x;
    int part = 0;
    for (int i = t; i < b; i += 256) part += cnts[i];
#pragma unroll
    for (int m = 1; m < 64; m <<= 1) part += __shfl_xor(part, m);
    if ((t & 63) == 0) obs[t >> 6] = part;
    int cnt = cnts[b];
    hist[t] = 0;
    if (t == 0) spill_cnt = 0;
    __syncthreads();
    int ob = obs[0] + obs[1] + obs[2] + obs[3];
    const int* sb = staging + b * BPAD;
    int ent[18], rnk[18];
#pragma unroll
    for (int u = 0; u < 18; ++u) {
        int i = u * 256 + t;
        ent[u] = -1;
        rnk[u] = 0;
        if (i < cnt) {
            int p = sb[i];
            ent[u] = p;
            rnk[u] = atomicAdd(&hist[p >> 17], 1);
        }
    }
    for (int i = 18 * 256 + t; i < cnt; i += 256) {
        int p = sb[i];
        int r = atomicAdd(&hist[p >> 17], 1);
        int si = atomicAdd(&spill_cnt, 1);
        spill[si][0] = p;
        spill[si][1] = r;
    }
    __syncthreads();
    int v0 = hist[t];
    int val = v0;
    sh[t] = val;
    __syncthreads();
    for (int off = 1; off < 256; off <<= 1) {
        int o = (t >= off) ? sh[t - off] : 0;
        __syncthreads();
        val += o;
        sh[t] = val;
        __syncthreads();
    }
    int excl = val - v0;
    int d = b * 256 + t;
    if (d < N_NODES) row_ptr[d] = ob + excl;
    __syncthreads();
    hist[t] = excl;
    __syncthreads();
#pragma unroll
    for (int u = 0; u < 18; ++u) {
        if (ent[u] >= 0) {
            int p = ent[u];
            sorted_src[ob + hist[p >> 17] + rnk[u]] = p & 0x1FFFF;
        }
    }
    for (int i = t; i < spill_cnt; i += 256) {
        int p = spill[i][0];
        sorted_src[ob + hist[p >> 17] + spill[i][1]] = p & 0x1FFFF;
    }
}

// ================= launch 1: partition (blocks 0..NPART-1) + transpose/init rest ==
// bnstat = bn1 partials (NSPLIT*256 floats) followed by bn2 acc (256 floats);
// zeroed by the first 33 transpose-region blocks.
__global__ __launch_bounds__(256) void k_prep(const int* __restrict__ ei,
                                              int* __restrict__ gcursor,
                                              int* __restrict__ staging,
                                              const float* __restrict__ W1,
                                              const float* __restrict__ W2,
                                              unsigned short* __restrict__ Wt1,
                                              unsigned short* __restrict__ Wt2,
                                              float* __restrict__ bnstat,
                                              int* __restrict__ row_ptr) {
    int t = threadIdx.x;
    if (blockIdx.x >= NPART) {
        int tb = blockIdx.x - NPART;
        int zi = tb * 256 + t;
        if (zi < NSPLIT * 256 + 256) bnstat[zi] = 0.f;
        if (zi == 0) row_ptr[N_NODES] = N_EDGES;
        int idx = tb * 256 + t;
        if (idx < IN_C * 128) {
            int k = idx >> 7, n = idx & 127;
            Wt1[n * IN_C + k] = f2bf(W1[idx]);
        } else {
            idx -= IN_C * 128;
            if (idx < HID * 128) {
                int k = idx >> 7, n = idx & 127;
                Wt2[n * HID + k] = f2bf(W2[idx]);
            }
        }
        return;
    }
    __shared__ int hist[NBUCK];
    __shared__ int loff[NBUCK];
    __shared__ int gbase[NBUCK];
    __shared__ int lstage[PART_E];
    __shared__ int gaddr[PART_E];
    __shared__ int scanbuf[512];
    int e0 = blockIdx.x * PART_E;
    int cntAll = min(PART_E, N_EDGES - e0);
    for (int i = t; i < NBUCK; i += 256) hist[i] = 0;
    __syncthreads();
    int pk[16];
    short bb[16], rr[16];
#pragma unroll
    for (int u = 0; u < 16; ++u) {
        int e = e0 + u * 256 + t;
        bb[u] = -1;
        rr[u] = 0;
        if (e < N_EDGES) {
            int s = ei[e], d = ei[N_EDGES + e];
            int b = d >> 8;
            int r = atomicAdd(&hist[b], 1);
            pk[u] = ((d & 255) << 17) | s;
            bb[u] = (short)b;
            rr[u] = (short)r;
        }
    }
    __syncthreads();
    scanbuf[t] = (t < NBUCK) ? hist[t] : 0;
    scanbuf[t + 256] = (t + 256 < NBUCK) ? hist[t + 256] : 0;
    __syncthreads();
    for (int off = 1; off < 512; off <<= 1) {
        int a0 = scanbuf[t];
        int a1 = scanbuf[t + 256];
        int b0 = (t >= off) ? scanbuf[t - off] : 0;
        int b1 = (t + 256 >= off) ? scanbuf[t + 256 - off] : 0;
        __syncthreads();
        scanbuf[t] = a0 + b0;
        scanbuf[t + 256] = a1 + b1;
        __syncthreads();
    }
    for (int i = t; i < NBUCK; i += 256) {
        loff[i] = scanbuf[i] - hist[i];
        gbase[i] = hist[i] ? atomicAdd(&gcursor[i], hist[i]) : 0;
    }
    __syncthreads();
#pragma unroll
    for (int u = 0; u < 16; ++u) {
        if (bb[u] >= 0) {
            int b = bb[u], r = rr[u];
            int pos = loff[b] + r;
            lstage[pos] = pk[u];
            gaddr[pos] = b * BPAD + gbase[b] + r;
        }
    }
    __syncthreads();
    for (int i = t; i < cntAll; i += 256) staging[gaddr[i]] = lstage[i];
}

// ================= launch 2: bucket_sort (blocks 0..NBUCK-1) || GEMM1 (rest) ======
__global__ __launch_bounds__(256) void k_gemm1_sort(const int* __restrict__ staging,
                                                    const int* __restrict__ cnts,
                                                    int* __restrict__ row_ptr,
                                                    int* __restrict__ sorted_src,
                                                    const float* __restrict__ x,
                                                    const unsigned short* __restrict__ Wt1,
                                                    unsigned short* __restrict__ hb,
                                                    const float* __restrict__ att_s,
                                                    const float* __restrict__ att_d,
                                                    float* __restrict__ a_src,
                                                    float* __restrict__ a_dst) {
    if (blockIdx.x < NBUCK) {
        bucket_sort_dev(blockIdx.x, staging, cnts, row_ptr, sorted_src);
    } else {
        gemm_dev<true, false, true, false>(blockIdx.x - NBUCK, x, Wt1, hb, IN_C,
                                           att_s, att_d, a_src, a_dst, nullptr);
    }
}

// ================= GEMM2 standalone (fused BN2 stats) =============================
__global__ __launch_bounds__(256) void k_gemm2(const void* __restrict__ Av,
                                               const unsigned short* __restrict__ Wt,
                                               void* __restrict__ Out,
                                               float* __restrict__ bnst) {
    gemm_dev<false, false, false, true>(blockIdx.x, Av, Wt, Out, HID,
                                        nullptr, nullptr, nullptr, nullptr, bnst);
}

// ---------------- GAT aggregate + fused BN1 stats (split atomic partials) ----------
// Block structure IDENTICAL to the proven R1/R3 shape (block = 4 nodes, short-lived
// waves, same inner loops). New: per-lane (sum,sumsq) of its 2 output channels,
// 4-wave LDS reduce, 256 atomics/block into partial copy blockIdx&(NSPLIT-1)
// (contention 25000/32 = 780/address, hidden under the 72us kernel).
// deg==0 waves skip the gather but JOIN the reduce with zeros (no early return).
__global__ __launch_bounds__(256) void k_gat_agg(const uint32* __restrict__ h32,
                                                 const float* __restrict__ a_src,
                                                 const float* __restrict__ a_dst,
                                                 const int* __restrict__ row_ptr,
                                                 const int* __restrict__ sorted_src,
                                                 uint32* __restrict__ out1,
                                                 float* __restrict__ bn1p) {
    __shared__ alignas(16) float wbuf[4][4][72];   // [wave][head][edge]
    __shared__ float sred[4][64][4];
    int lane = threadIdx.x & 63, wv = threadIdx.x >> 6;
    int hd = lane >> 4;
    int node = blockIdx.x * 4 + wv;
    int start = row_ptr[node];
    int deg = row_ptr[node + 1] - start;
    float o0 = 0.f, o1 = 0.f;
    if (deg != 0) {
        float4 ad = *(const float4*)&a_dst[node * 4];
        float acc0 = 0.f, acc1 = 0.f, den = 0.f;
        for (int j0 = 0; j0 < deg; j0 += 64) {
            int m = min(64, deg - j0);
            int s = 0;
            float4 w = make_float4(0.f, 0.f, 0.f, 0.f);
            if (lane < m) {
                s = sorted_src[start + j0 + lane];
                float4 as = *(const float4*)&a_src[s * 4];
                w.x = __expf(lrelu(as.x + ad.x));
                w.y = __expf(lrelu(as.y + ad.y));
                w.z = __expf(lrelu(as.z + ad.z));
                w.w = __expf(lrelu(as.w + ad.w));
            }
            wbuf[wv][0][lane] = w.x;
            wbuf[wv][1][lane] = w.y;
            wbuf[wv][2][lane] = w.z;
            wbuf[wv][3][lane] = w.w;
            __builtin_amdgcn_wave_barrier();
            int e0 = 0;
            for (; e0 + 8 <= m; e0 += 8) {
                uint32 hr[8];
#pragma unroll
                for (int k = 0; k < 8; ++k) {
                    int ss = __builtin_amdgcn_readlane(s, e0 + k);
                    hr[k] = h32[((uint32)ss << 6) + lane];
                }
                float4 w0 = *(const float4*)&wbuf[wv][hd][e0];
                float4 w1 = *(const float4*)&wbuf[wv][hd][e0 + 4];
                float wk[8] = {w0.x, w0.y, w0.z, w0.w, w1.x, w1.y, w1.z, w1.w};
#pragma unroll
                for (int k = 0; k < 8; ++k) {
                    den += wk[k];
                    acc0 = fmaf(wk[k], bflo(hr[k]), acc0);
                    acc1 = fmaf(wk[k], bfhi(hr[k]), acc1);
                }
            }
            for (; e0 < m; ++e0) {
                int ss = __builtin_amdgcn_readlane(s, e0);
                uint32 hv = h32[((uint32)ss << 6) + lane];
                float wk = wbuf[wv][hd][e0];
                den += wk;
                acc0 = fmaf(wk, bflo(hv), acc0);
                acc1 = fmaf(wk, bfhi(hv), acc1);
            }
            __builtin_amdgcn_wave_barrier();
        }
        float rden = 1.f / den;
        o0 = acc0 * rden;
        o1 = acc1 * rden;
    }
    out1[((uint32)node << 6) + lane] = packbf(o0, o1);
    sred[wv][lane][0] = o0;
    sred[wv][lane][1] = o1;
    sred[wv][lane][2] = o0 * o0;
    sred[wv][lane][3] = o1 * o1;
    __syncthreads();
    if (wv == 0) {
        float s0 = sred[0][lane][0] + sred[1][lane][0] + sred[2][lane][0] + sred[3][lane][0];
        float s1 = sred[0][lane][1] + sred[1][lane][1] + sred[2][lane][1] + sred[3][lane][1];
        float q0 = sred[0][lane][2] + sred[1][lane][2] + sred[2][lane][2] + sred[3][lane][2];
        float q1 = sred[0][lane][3] + sred[1][lane][3] + sred[2][lane][3] + sred[3][lane][3];
        float* dst = bn1p + (blockIdx.x & (NSPLIT - 1)) * 256;
        int c0 = lane * 2;
        atomicAdd(&dst[c0], s0);
        atomicAdd(&dst[c0 + 1], s1);
        atomicAdd(&dst[128 + c0], q0);
        atomicAdd(&dst[128 + c0 + 1], q1);
    }
}

// ---------------- GIN aggregate with fused BN1+ELU on gathered rows --------------
// Reduces the NSPLIT partial-stat copies at block start (L2-hot, ~256KB total),
// then identical gather with register BN params.
__global__ __launch_bounds__(256) void k_gin_agg(const uint32* __restrict__ ob,
                                                 const int* __restrict__ row_ptr,
                                                 const int* __restrict__ sorted_src,
                                                 const float* __restrict__ eps_ptr,
                                                 const float* __restrict__ bn1p,
                                                 const float* __restrict__ gamma,
                                                 const float* __restrict__ beta,
                                                 uint32* __restrict__ zb) {
    __shared__ float stot[256];
    int t = threadIdx.x;
    float v = 0.f;
#pragma unroll
    for (int k = 0; k < NSPLIT; ++k) v += bn1p[k * 256 + t];
    stot[t] = v;
    __syncthreads();
    int lane = t & 63, wv = t >> 6;
    int c0 = lane * 2;
    float mu0 = stot[c0] * (1.f / N_NODES), mu1 = stot[c0 + 1] * (1.f / N_NODES);
    float va0 = stot[128 + c0] * (1.f / N_NODES) - mu0 * mu0;
    float va1 = stot[128 + c0 + 1] * (1.f / N_NODES) - mu1 * mu1;
    float s0 = rsqrtf(va0 + BN_EPS) * gamma[c0];
    float s1 = rsqrtf(va1 + BN_EPS) * gamma[c0 + 1];
    float h0 = beta[c0] - mu0 * s0;
    float h1 = beta[c0 + 1] - mu1 * s1;
    int node = blockIdx.x * 4 + wv;
    int start = row_ptr[node];
    int deg = row_ptr[node + 1] - start;
    float acc0 = 0.f, acc1 = 0.f;
    for (int j0 = 0; j0 < deg; j0 += 64) {
        int m = min(64, deg - j0);
        int s = 0;
        if (lane < m) s = sorted_src[start + j0 + lane];
        int e0 = 0;
        for (; e0 + 8 <= m; e0 += 8) {
            uint32 hr[8];
#pragma unroll
            for (int k = 0; k < 8; ++k) {
                int ss = __builtin_amdgcn_readlane(s, e0 + k);
                hr[k] = ob[((uint32)ss << 6) + lane];
            }
#pragma unroll
            for (int k = 0; k < 8; ++k) {
                float f0 = fmaf(bflo(hr[k]), s0, h0);
                float f1 = fmaf(bfhi(hr[k]), s1, h1);
                acc0 += f0 > 0.f ? f0 : __expf(f0) - 1.f;
                acc1 += f1 > 0.f ? f1 : __expf(f1) - 1.f;
            }
        }
        for (; e0 < m; ++e0) {
            int ss = __builtin_amdgcn_readlane(s, e0);
            uint32 hv = ob[((uint32)ss << 6) + lane];
            float f0 = fmaf(bflo(hv), s0, h0);
            float f1 = fmaf(bfhi(hv), s1, h1);
            acc0 += f0 > 0.f ? f0 : __expf(f0) - 1.f;
            acc1 += f1 > 0.f ? f1 : __expf(f1) - 1.f;
        }
    }
    float ep = 1.f + eps_ptr[0];
    uint32 own = ob[((uint32)node << 6) + lane];
    float f0 = fmaf(bflo(own), s0, h0);
    float f1 = fmaf(bfhi(own), s1, h1);
    f0 = f0 > 0.f ? f0 : __expf(f0) - 1.f;
    f1 = f1 > 0.f ? f1 : __expf(f1) - 1.f;
    zb[((uint32)node << 6) + lane] = packbf(fmaf(ep, f0, acc0), fmaf(ep, f1, acc1));
}

// ---------------- BN + ELU: bf16 in -> fp32 out (grid-stride, register params) ------
__global__ __launch_bounds__(256) void k_bn_elu_out(const uint32* __restrict__ in,
                                                    const float* __restrict__ acc,
                                                    const float* __restrict__ gamma,
                                                    const float* __restrict__ beta,
                                                    float2* __restrict__ out) {
    int t = threadIdx.x;
    int c0 = (t & 63) * 2;
    float mu0 = acc[c0] * (1.f / N_NODES), mu1 = acc[c0 + 1] * (1.f / N_NODES);
    float va0 = acc[128 + c0] * (1.f / N_NODES) - mu0 * mu0;
    float va1 = acc[128 + c0 + 1] * (1.f / N_NODES) - mu1 * mu1;
    float s0 = rsqrtf(va0 + BN_EPS) * gamma[c0];
    float s1 = rsqrtf(va1 + BN_EPS) * gamma[c0 + 1];
    float h0 = beta[c0] - mu0 * s0;
    float h1 = beta[c0 + 1] - mu1 * s1;
    for (size_t i = (size_t)blockIdx.x * 256 + t; i < (size_t)N_NODES * 64;
         i += (size_t)ELEM_BLOCKS * 256) {
        uint32 v = in[i];
        float r0 = fmaf(bflo(v), s0, h0);
        float r1 = fmaf(bfhi(v), s1, h1);
        r0 = r0 > 0.f ? r0 : __expf(r0) - 1.f;
        r1 = r1 > 0.f ? r1 : __expf(r1) - 1.f;
        out[i] = make_float2(r0, r1);
    }
}

extern "C" void kernel_launch(void* const* d_in, const int* in_sizes, int n_in,
                              void* d_out, int out_size, void* d_ws, size_t ws_size,
                              hipStream_t stream) {
    (void)in_sizes; (void)n_in; (void)out_size; (void)ws_size;
    const float* x       = (const float*)d_in[0];
    const float* W_gat   = (const float*)d_in[1];
    const float* att_src = (const float*)d_in[2];
    const float* att_dst = (const float*)d_in[3];
    // bias_gat / lin_b cancel exactly under batch-norm -> dropped
    const float* bn1_g   = (const float*)d_in[5];
    const float* bn1_b   = (const float*)d_in[6];
    const float* eps_gin = (const float*)d_in[7];
    const float* lin_W   = (const float*)d_in[8];
    const float* bn2_g   = (const float*)d_in[10];
    const float* bn2_b   = (const float*)d_in[11];
    const int*   ei      = (const int*)d_in[12];
    float* out = (float*)d_out;

    char* w = (char*)d_ws;
    size_t o = 0;
    auto take = [&](size_t b) -> char* {
        char* p = w + o;
        o += (b + 255) & ~(size_t)255;
        return p;
    };
    unsigned short* hb   = (unsigned short*)take((size_t)N_NODES * 128 * 2);
    unsigned short* Wt1  = (unsigned short*)take((size_t)128 * IN_C * 2);
    unsigned short* Wt2  = (unsigned short*)take((size_t)128 * HID * 2);
    uint32* o1b          = (uint32*)take((size_t)N_NODES * 64 * 4);
    float* a_src         = (float*)take((size_t)N_NODES * 4 * 4);
    float* a_dst         = (float*)take((size_t)N_NODES * 4 * 4);
    int*   sorted        = (int*)take((size_t)N_EDGES * 4);
    int*   staging       = (int*)take((size_t)NBUCK * BPAD * 4);
    int*   row_ptr       = (int*)take((size_t)(N_NODES + 1) * 4);
    int*   gcursor       = (int*)take((NBUCK + 1) * 4);
    float* bnstat        = (float*)take((NSPLIT * 256 + 256) * 4); // bn1 partials + bn2
    float* bn1p          = bnstat;
    float* bn2acc        = bnstat + NSPLIT * 256;
    uint32* zb  = (uint32*)hb;  // reuse: hb dead after k_gat_agg
    uint32* o2b = o1b;          // reuse: o1b dead after k_gin_agg reads it
    const int nGemmBlocks = (N_NODES + 127) / 128;

    // zero gcursor only (bnstat zeroed inside k_prep transpose region)
    hipMemsetAsync(gcursor, 0, (NBUCK + 1) * sizeof(int), stream);
    k_prep<<<NPART + TBLOCKS, 256, 0, stream>>>(ei, gcursor, staging, W_gat, lin_W,
                                                Wt1, Wt2, bnstat, row_ptr);
    k_gemm1_sort<<<NBUCK + nGemmBlocks, 256, 0, stream>>>(
        staging, gcursor, row_ptr, sorted, x, Wt1, hb, att_src, att_dst, a_src, a_dst);
    k_gat_agg<<<N_NODES / 4, 256, 0, stream>>>((const uint32*)hb, a_src, a_dst, row_ptr,
                                               sorted, o1b, bn1p);
    k_gin_agg<<<N_NODES / 4, 256, 0, stream>>>(o1b, row_ptr, sorted, eps_gin, bn1p,
                                               bn1_g, bn1_b, zb);
    k_gemm2<<<nGemmBlocks, 256, 0, stream>>>(zb, Wt2, o2b, bn2acc);
    k_bn_elu_out<<<ELEM_BLOCKS, 256, 0, stream>>>(o2b, bn2acc, bn2_g, bn2_b,
                                                  (float2*)out);
}

// Round 9
// 466.151 us; speedup vs baseline: 1.0748x; 1.0294x over previous
//
#include <hip/hip_runtime.h>
#include <hip/hip_cooperative_groups.h>

#define N_NODES 100000
#define N_EDGES 1600000
#define IN_C 256
#define HID 128
#define NEG_SLOPE 0.2f
#define BN_EPS 1e-5f
#define NBUCK 391          // ceil(N_NODES/256): bucket b covers dst [b*256,(b+1)*256)
#define NPART 391          // ceil(N_EDGES/4096) partition tiles
#define PART_E 4096        // edges per partition block
#define BPAD 5120          // padded per-bucket staging stride (mean 4096 + 16 sigma)
#define TBLOCKS 192        // transpose blocks: (IN_C+HID)*128/256
#define NSPLIT 32          // BN1 partial-stat buffer copies
#define GAT_NPB 8          // nodes (waves) per gat block: halves stat-atomic count
#define ELEM_BLOCKS 2048   // grid-stride blocks for elementwise BN kernels

typedef unsigned int uint32;
typedef __attribute__((ext_vector_type(8))) short bf16x8;
typedef __attribute__((ext_vector_type(4))) float f32x4;

__device__ __forceinline__ float lrelu(float x) { return x > 0.f ? x : NEG_SLOPE * x; }

__device__ __forceinline__ unsigned short f2bf(float f) {
    uint32 u = __float_as_uint(f);
    u += 0x7fffu + ((u >> 16) & 1u);
    return (unsigned short)(u >> 16);
}
__device__ __forceinline__ float bf2f(unsigned short h) {
    return __uint_as_float(((uint32)h) << 16);
}
__device__ __forceinline__ float bflo(uint32 v) { return __uint_as_float(v << 16); }
__device__ __forceinline__ float bfhi(uint32 v) { return __uint_as_float(v & 0xffff0000u); }
__device__ __forceinline__ uint32 packbf(float a, float b) {
    return (uint32)f2bf(a) | ((uint32)f2bf(b) << 16);
}

// ================= GEMM device body ===============================================
// ATT:    fuse GAT attention dot-products into the epilogue.
// STATS:  fuse BN column stats (sum, sumsq) into the epilogue.
// FUSEBN: cooperative path -- skip bf16 store, grid.sync(), then BN+ELU the
//         register accumulator and write fp32 output directly.
template <bool AF32, bool OUTF32, bool ATT, bool STATS, bool FUSEBN = false>
__device__ __forceinline__ void gemm_dev(int bid, const void* __restrict__ Av,
                                         const unsigned short* __restrict__ Wt,
                                         void* __restrict__ Out, int K,
                                         const float* __restrict__ att_s,
                                         const float* __restrict__ att_d,
                                         float* __restrict__ a_src,
                                         float* __restrict__ a_dst,
                                         float* __restrict__ bnst,
                                         const float* __restrict__ gamma = nullptr,
                                         const float* __restrict__ beta = nullptr,
                                         float* __restrict__ fout = nullptr) {
    __shared__ unsigned short As[128 * 72];
    __shared__ unsigned short Bs[128 * 72];
    const int t = threadIdx.x;
    const int n0 = bid * 128;
    const int wv = t >> 6, lane = t & 63;
    const int wy = wv >> 1, wx = wv & 1;
    const int lm = lane & 15, lg = lane >> 4;
    const float* Af = (const float*)Av;
    const unsigned short* Ah = (const unsigned short*)Av;

    f32x4 acc[4][4];
#pragma unroll
    for (int i = 0; i < 4; ++i)
#pragma unroll
        for (int j = 0; j < 4; ++j) acc[i][j] = (f32x4){0.f, 0.f, 0.f, 0.f};

    float4 afp[8];
    uint4 ahp[4];
    uint4 bvp[4];

    if (AF32) {
#pragma unroll
        for (int p = 0; p < 8; ++p) {
            int idx = p * 256 + t, row = idx >> 4, c4 = idx & 15, gn = n0 + row;
            afp[p] = (gn < N_NODES) ? *(const float4*)&Af[(size_t)gn * K + c4 * 4]
                                    : make_float4(0.f, 0.f, 0.f, 0.f);
        }
    } else {
#pragma unroll
        for (int p = 0; p < 4; ++p) {
            int idx = p * 256 + t, row = idx >> 3, c = idx & 7, gn = n0 + row;
            ahp[p] = (gn < N_NODES) ? *(const uint4*)&Ah[(size_t)gn * K + c * 8]
                                    : make_uint4(0, 0, 0, 0);
        }
    }
#pragma unroll
    for (int p = 0; p < 4; ++p) {
        int idx = p * 256 + t, n = idx >> 3, c = idx & 7;
        bvp[p] = *(const uint4*)&Wt[(size_t)n * K + c * 8];
    }

    for (int kc = 0; kc < K; kc += 64) {
        if (AF32) {
#pragma unroll
            for (int p = 0; p < 8; ++p) {
                int idx = p * 256 + t, row = idx >> 4, c4 = idx & 15;
                ushort4 b;
                b.x = f2bf(afp[p].x); b.y = f2bf(afp[p].y);
                b.z = f2bf(afp[p].z); b.w = f2bf(afp[p].w);
                *(ushort4*)&As[row * 72 + c4 * 4] = b;
            }
        } else {
#pragma unroll
            for (int p = 0; p < 4; ++p) {
                int idx = p * 256 + t, row = idx >> 3, c = idx & 7;
                *(uint4*)&As[row * 72 + c * 8] = ahp[p];
            }
        }
#pragma unroll
        for (int p = 0; p < 4; ++p) {
            int idx = p * 256 + t, n = idx >> 3, c = idx & 7;
            *(uint4*)&Bs[n * 72 + c * 8] = bvp[p];
        }
        __syncthreads();
        int kn = kc + 64;
        if (kn < K) {
            if (AF32) {
#pragma unroll
                for (int p = 0; p < 8; ++p) {
                    int idx = p * 256 + t, row = idx >> 4, c4 = idx & 15, gn = n0 + row;
                    afp[p] = (gn < N_NODES) ? *(const float4*)&Af[(size_t)gn * K + kn + c4 * 4]
                                            : make_float4(0.f, 0.f, 0.f, 0.f);
                }
            } else {
#pragma unroll
                for (int p = 0; p < 4; ++p) {
                    int idx = p * 256 + t, row = idx >> 3, c = idx & 7, gn = n0 + row;
                    ahp[p] = (gn < N_NODES) ? *(const uint4*)&Ah[(size_t)gn * K + kn + c * 8]
                                            : make_uint4(0, 0, 0, 0);
                }
            }
#pragma unroll
            for (int p = 0; p < 4; ++p) {
                int idx = p * 256 + t, n = idx >> 3, c = idx & 7;
                bvp[p] = *(const uint4*)&Wt[(size_t)n * K + kn + c * 8];
            }
        }
#pragma unroll
        for (int ks = 0; ks < 2; ++ks) {
            bf16x8 af[4], bfr[4];
#pragma unroll
            for (int i = 0; i < 4; ++i)
                af[i] = *(const bf16x8*)&As[(wy * 64 + i * 16 + lm) * 72 + ks * 32 + lg * 8];
#pragma unroll
            for (int j = 0; j < 4; ++j)
                bfr[j] = *(const bf16x8*)&Bs[(wx * 64 + j * 16 + lm) * 72 + ks * 32 + lg * 8];
#pragma unroll
            for (int i = 0; i < 4; ++i)
#pragma unroll
                for (int j = 0; j < 4; ++j)
                    acc[i][j] = __builtin_amdgcn_mfma_f32_16x16x32_bf16(af[i], bfr[j],
                                                                        acc[i][j], 0, 0, 0);
        }
        __syncthreads();
    }

    // ---- epilogue ----
    float as_w[4], ad_w[4];
    if (ATT) {
#pragma unroll
        for (int j = 0; j < 4; ++j) {
            int col = wx * 64 + j * 16 + lm;
            as_w[j] = att_s[col];
            ad_w[j] = att_d[col];
        }
    }
    float ls[4] = {0.f, 0.f, 0.f, 0.f}, lq[4] = {0.f, 0.f, 0.f, 0.f};
#pragma unroll
    for (int i = 0; i < 4; ++i) {
#pragma unroll
        for (int r = 0; r < 4; ++r) {
            int row = n0 + wy * 64 + i * 16 + lg * 4 + r;
            float v0 = acc[i][0][r], v1 = acc[i][1][r];
            float v2 = acc[i][2][r], v3 = acc[i][3][r];
            if constexpr (!FUSEBN) {
                if (row < N_NODES) {
                    if (OUTF32) {
                        float* op = (float*)Out + (size_t)row * 128 + wx * 64 + lm;
                        op[0] = v0; op[16] = v1; op[32] = v2; op[48] = v3;
                    } else {
                        unsigned short* op =
                            (unsigned short*)Out + (size_t)row * 128 + wx * 64 + lm;
                        op[0] = f2bf(v0); op[16] = f2bf(v1);
                        op[32] = f2bf(v2); op[48] = f2bf(v3);
                    }
                }
            }
            if (STATS) {  // padded rows contribute exact zeros (A zero-filled)
                ls[0] += v0; lq[0] += v0 * v0;
                ls[1] += v1; lq[1] += v1 * v1;
                ls[2] += v2; lq[2] += v2 * v2;
                ls[3] += v3; lq[3] += v3 * v3;
            }
            if (ATT) {
                float ps0 = v0 * as_w[0] + v1 * as_w[1];
                float ps1 = v2 * as_w[2] + v3 * as_w[3];
                float pd0 = v0 * ad_w[0] + v1 * ad_w[1];
                float pd1 = v2 * ad_w[2] + v3 * ad_w[3];
#pragma unroll
                for (int m = 1; m < 16; m <<= 1) {
                    ps0 += __shfl_xor(ps0, m); ps1 += __shfl_xor(ps1, m);
                    pd0 += __shfl_xor(pd0, m); pd1 += __shfl_xor(pd1, m);
                }
                if (lm == 0 && row < N_NODES) {
                    *(float2*)&a_src[row * 4 + wx * 2] = make_float2(ps0, ps1);
                    *(float2*)&a_dst[row * 4 + wx * 2] = make_float2(pd0, pd1);
                }
            }
        }
    }
    if (STATS) {
#pragma unroll
        for (int j = 0; j < 4; ++j) {
            float s = ls[j], q = lq[j];
            s += __shfl_xor(s, 16); s += __shfl_xor(s, 32);
            q += __shfl_xor(q, 16); q += __shfl_xor(q, 32);
            if (lg == 0) {
                int col = wx * 64 + j * 16 + lm;
                atomicAdd(&bnst[col], s);
                atomicAdd(&bnst[128 + col], q);
            }
        }
    }
    if constexpr (FUSEBN) {
        cooperative_groups::this_grid().sync();
        float sc[4], sh2[4];
#pragma unroll
        for (int j = 0; j < 4; ++j) {
            int col = wx * 64 + j * 16 + lm;
            float mu = bnst[col] * (1.f / N_NODES);
            float var = bnst[128 + col] * (1.f / N_NODES) - mu * mu;
            sc[j] = rsqrtf(var + BN_EPS) * gamma[col];
            sh2[j] = beta[col] - mu * sc[j];
        }
#pragma unroll
        for (int i = 0; i < 4; ++i) {
#pragma unroll
            for (int r = 0; r < 4; ++r) {
                int row = n0 + wy * 64 + i * 16 + lg * 4 + r;
                if (row < N_NODES) {
                    float* op = fout + (size_t)row * 128 + wx * 64 + lm;
#pragma unroll
                    for (int j = 0; j < 4; ++j) {
                        float v = fmaf(acc[i][j][r], sc[j], sh2[j]);
                        v = v > 0.f ? v : __expf(v) - 1.f;
                        op[j * 16] = v;
                    }
                }
            }
        }
    }
}

// ================= bucket_sort device body ========================================
__device__ __forceinline__ void bucket_sort_dev(int b, const int* __restrict__ staging,
                                                const int* __restrict__ cnts,
                                                int* __restrict__ row_ptr,
                                                int* __restrict__ sorted_src) {
    __shared__ int hist[256];
    __shared__ int sh[256];
    __shared__ int spill[256][2];
    __shared__ int spill_cnt;
    __shared__ int obs[4];
    int t = threadIdx.x;
    int part = 0;
    for (int i = t; i < b; i += 256) part += cnts[i];
#pragma unroll
    for (int m = 1; m < 64; m <<= 1) part += __shfl_xor(part, m);
    if ((t & 63) == 0) obs[t >> 6] = part;
    int cnt = cnts[b];
    hist[t] = 0;
    if (t == 0) spill_cnt = 0;
    __syncthreads();
    int ob = obs[0] + obs[1] + obs[2] + obs[3];
    const int* sb = staging + b * BPAD;
    int ent[18], rnk[18];
#pragma unroll
    for (int u = 0; u < 18; ++u) {
        int i = u * 256 + t;
        ent[u] = -1;
        rnk[u] = 0;
        if (i < cnt) {
            int p = sb[i];
            ent[u] = p;
            rnk[u] = atomicAdd(&hist[p >> 17], 1);
        }
    }
    for (int i = 18 * 256 + t; i < cnt; i += 256) {
        int p = sb[i];
        int r = atomicAdd(&hist[p >> 17], 1);
        int si = atomicAdd(&spill_cnt, 1);
        spill[si][0] = p;
        spill[si][1] = r;
    }
    __syncthreads();
    int v0 = hist[t];
    int val = v0;
    sh[t] = val;
    __syncthreads();
    for (int off = 1; off < 256; off <<= 1) {
        int o = (t >= off) ? sh[t - off] : 0;
        __syncthreads();
        val += o;
        sh[t] = val;
        __syncthreads();
    }
    int excl = val - v0;
    int d = b * 256 + t;
    if (d < N_NODES) row_ptr[d] = ob + excl;
    __syncthreads();
    hist[t] = excl;
    __syncthreads();
#pragma unroll
    for (int u = 0; u < 18; ++u) {
        if (ent[u] >= 0) {
            int p = ent[u];
            sorted_src[ob + hist[p >> 17] + rnk[u]] = p & 0x1FFFF;
        }
    }
    for (int i = t; i < spill_cnt; i += 256) {
        int p = spill[i][0];
        sorted_src[ob + hist[p >> 17] + spill[i][1]] = p & 0x1FFFF;
    }
}

// ================= launch 1: partition (blocks 0..NPART-1) + transpose/init rest ==
__global__ __launch_bounds__(256) void k_prep(const int* __restrict__ ei,
                                              int* __restrict__ gcursor,
                                              int* __restrict__ staging,
                                              const float* __restrict__ W1,
                                              const float* __restrict__ W2,
                                              unsigned short* __restrict__ Wt1,
                                              unsigned short* __restrict__ Wt2,
                                              float* __restrict__ bnstat,
                                              int* __restrict__ row_ptr) {
    int t = threadIdx.x;
    if (blockIdx.x >= NPART) {
        int tb = blockIdx.x - NPART;
        int zi = tb * 256 + t;
        if (zi < NSPLIT * 256 + 256) bnstat[zi] = 0.f;
        if (zi == 0) row_ptr[N_NODES] = N_EDGES;
        int idx = tb * 256 + t;
        if (idx < IN_C * 128) {
            int k = idx >> 7, n = idx & 127;
            Wt1[n * IN_C + k] = f2bf(W1[idx]);
        } else {
            idx -= IN_C * 128;
            if (idx < HID * 128) {
                int k = idx >> 7, n = idx & 127;
                Wt2[n * HID + k] = f2bf(W2[idx]);
            }
        }
        return;
    }
    __shared__ int hist[NBUCK];
    __shared__ int loff[NBUCK];
    __shared__ int gbase[NBUCK];
    __shared__ int lstage[PART_E];
    __shared__ int gaddr[PART_E];
    __shared__ int scanbuf[512];
    int e0 = blockIdx.x * PART_E;
    int cntAll = min(PART_E, N_EDGES - e0);
    for (int i = t; i < NBUCK; i += 256) hist[i] = 0;
    __syncthreads();
    int pk[16];
    short bb[16], rr[16];
#pragma unroll
    for (int u = 0; u < 16; ++u) {
        int e = e0 + u * 256 + t;
        bb[u] = -1;
        rr[u] = 0;
        if (e < N_EDGES) {
            int s = ei[e], d = ei[N_EDGES + e];
            int b = d >> 8;
            int r = atomicAdd(&hist[b], 1);
            pk[u] = ((d & 255) << 17) | s;
            bb[u] = (short)b;
            rr[u] = (short)r;
        }
    }
    __syncthreads();
    scanbuf[t] = (t < NBUCK) ? hist[t] : 0;
    scanbuf[t + 256] = (t + 256 < NBUCK) ? hist[t + 256] : 0;
    __syncthreads();
    for (int off = 1; off < 512; off <<= 1) {
        int a0 = scanbuf[t];
        int a1 = scanbuf[t + 256];
        int b0 = (t >= off) ? scanbuf[t - off] : 0;
        int b1 = (t + 256 >= off) ? scanbuf[t + 256 - off] : 0;
        __syncthreads();
        scanbuf[t] = a0 + b0;
        scanbuf[t + 256] = a1 + b1;
        __syncthreads();
    }
    for (int i = t; i < NBUCK; i += 256) {
        loff[i] = scanbuf[i] - hist[i];
        gbase[i] = hist[i] ? atomicAdd(&gcursor[i], hist[i]) : 0;
    }
    __syncthreads();
#pragma unroll
    for (int u = 0; u < 16; ++u) {
        if (bb[u] >= 0) {
            int b = bb[u], r = rr[u];
            int pos = loff[b] + r;
            lstage[pos] = pk[u];
            gaddr[pos] = b * BPAD + gbase[b] + r;
        }
    }
    __syncthreads();
    for (int i = t; i < cntAll; i += 256) staging[gaddr[i]] = lstage[i];
}

// ================= launch 2: bucket_sort (blocks 0..NBUCK-1) || GEMM1 (rest) ======
__global__ __launch_bounds__(256) void k_gemm1_sort(const int* __restrict__ staging,
                                                    const int* __restrict__ cnts,
                                                    int* __restrict__ row_ptr,
                                                    int* __restrict__ sorted_src,
                                                    const float* __restrict__ x,
                                                    const unsigned short* __restrict__ Wt1,
                                                    unsigned short* __restrict__ hb,
                                                    const float* __restrict__ att_s,
                                                    const float* __restrict__ att_d,
                                                    float* __restrict__ a_src,
                                                    float* __restrict__ a_dst) {
    if (blockIdx.x < NBUCK) {
        bucket_sort_dev(blockIdx.x, staging, cnts, row_ptr, sorted_src);
    } else {
        gemm_dev<true, false, true, false>(blockIdx.x - NBUCK, x, Wt1, hb, IN_C,
                                           att_s, att_d, a_src, a_dst, nullptr);
    }
}

// ================= GEMM2 variants =================================================
// Cooperative: GEMM + BN2 stats + grid.sync + BN/ELU from registers -> fp32 out.
__global__ __launch_bounds__(256, 4) void k_gemm2_bn(const void* __restrict__ Av,
                                                     const unsigned short* __restrict__ Wt,
                                                     float* __restrict__ bnst,
                                                     const float* __restrict__ gamma,
                                                     const float* __restrict__ beta,
                                                     float* __restrict__ fout) {
    gemm_dev<false, false, false, true, true>(blockIdx.x, Av, Wt, nullptr, HID,
                                              nullptr, nullptr, nullptr, nullptr,
                                              bnst, gamma, beta, fout);
}

// Fallback pair (used if cooperative launch unavailable).
__global__ __launch_bounds__(256) void k_gemm2(const void* __restrict__ Av,
                                               const unsigned short* __restrict__ Wt,
                                               void* __restrict__ Out,
                                               float* __restrict__ bnst) {
    gemm_dev<false, false, false, true>(blockIdx.x, Av, Wt, Out, HID,
                                        nullptr, nullptr, nullptr, nullptr, bnst);
}

__global__ __launch_bounds__(256) void k_bn_elu_out(const uint32* __restrict__ in,
                                                    const float* __restrict__ acc,
                                                    const float* __restrict__ gamma,
                                                    const float* __restrict__ beta,
                                                    float2* __restrict__ out) {
    int t = threadIdx.x;
    int c0 = (t & 63) * 2;
    float mu0 = acc[c0] * (1.f / N_NODES), mu1 = acc[c0 + 1] * (1.f / N_NODES);
    float va0 = acc[128 + c0] * (1.f / N_NODES) - mu0 * mu0;
    float va1 = acc[128 + c0 + 1] * (1.f / N_NODES) - mu1 * mu1;
    float s0 = rsqrtf(va0 + BN_EPS) * gamma[c0];
    float s1 = rsqrtf(va1 + BN_EPS) * gamma[c0 + 1];
    float h0 = beta[c0] - mu0 * s0;
    float h1 = beta[c0 + 1] - mu1 * s1;
    for (size_t i = (size_t)blockIdx.x * 256 + t; i < (size_t)N_NODES * 64;
         i += (size_t)ELEM_BLOCKS * 256) {
        uint32 v = in[i];
        float r0 = fmaf(bflo(v), s0, h0);
        float r1 = fmaf(bfhi(v), s1, h1);
        r0 = r0 > 0.f ? r0 : __expf(r0) - 1.f;
        r1 = r1 > 0.f ? r1 : __expf(r1) - 1.f;
        out[i] = make_float2(r0, r1);
    }
}

// ---------------- GAT aggregate + fused BN1 stats, 8 waves/block ------------------
// Per-wave gather structure IDENTICAL to the proven shape (1 node/wave, same inner
// loops). 8 nodes/block halves the device-atomic count (12500 x 256 = 3.2M) that
// R8's counters identified as the +25us/+50MB cost.
__global__ __launch_bounds__(512) void k_gat_agg(const uint32* __restrict__ h32,
                                                 const float* __restrict__ a_src,
                                                 const float* __restrict__ a_dst,
                                                 const int* __restrict__ row_ptr,
                                                 const int* __restrict__ sorted_src,
                                                 uint32* __restrict__ out1,
                                                 float* __restrict__ bn1p) {
    __shared__ alignas(16) float wbuf[GAT_NPB][4][72];   // [wave][head][edge]
    __shared__ float sred[GAT_NPB][64][4];
    int lane = threadIdx.x & 63, wv = threadIdx.x >> 6;
    int hd = lane >> 4;
    int node = blockIdx.x * GAT_NPB + wv;
    int start = row_ptr[node];
    int deg = row_ptr[node + 1] - start;
    float o0 = 0.f, o1 = 0.f;
    if (deg != 0) {
        float4 ad = *(const float4*)&a_dst[node * 4];
        float acc0 = 0.f, acc1 = 0.f, den = 0.f;
        for (int j0 = 0; j0 < deg; j0 += 64) {
            int m = min(64, deg - j0);
            int s = 0;
            float4 w = make_float4(0.f, 0.f, 0.f, 0.f);
            if (lane < m) {
                s = sorted_src[start + j0 + lane];
                float4 as = *(const float4*)&a_src[s * 4];
                w.x = __expf(lrelu(as.x + ad.x));
                w.y = __expf(lrelu(as.y + ad.y));
                w.z = __expf(lrelu(as.z + ad.z));
                w.w = __expf(lrelu(as.w + ad.w));
            }
            wbuf[wv][0][lane] = w.x;
            wbuf[wv][1][lane] = w.y;
            wbuf[wv][2][lane] = w.z;
            wbuf[wv][3][lane] = w.w;
            __builtin_amdgcn_wave_barrier();
            int e0 = 0;
            for (; e0 + 8 <= m; e0 += 8) {
                uint32 hr[8];
#pragma unroll
                for (int k = 0; k < 8; ++k) {
                    int ss = __builtin_amdgcn_readlane(s, e0 + k);
                    hr[k] = h32[((uint32)ss << 6) + lane];
                }
                float4 w0 = *(const float4*)&wbuf[wv][hd][e0];
                float4 w1 = *(const float4*)&wbuf[wv][hd][e0 + 4];
                float wk[8] = {w0.x, w0.y, w0.z, w0.w, w1.x, w1.y, w1.z, w1.w};
#pragma unroll
                for (int k = 0; k < 8; ++k) {
                    den += wk[k];
                    acc0 = fmaf(wk[k], bflo(hr[k]), acc0);
                    acc1 = fmaf(wk[k], bfhi(hr[k]), acc1);
                }
            }
            for (; e0 < m; ++e0) {
                int ss = __builtin_amdgcn_readlane(s, e0);
                uint32 hv = h32[((uint32)ss << 6) + lane];
                float wk = wbuf[wv][hd][e0];
                den += wk;
                acc0 = fmaf(wk, bflo(hv), acc0);
                acc1 = fmaf(wk, bfhi(hv), acc1);
            }
            __builtin_amdgcn_wave_barrier();
        }
        float rden = 1.f / den;
        o0 = acc0 * rden;
        o1 = acc1 * rden;
    }
    out1[((uint32)node << 6) + lane] = packbf(o0, o1);
    sred[wv][lane][0] = o0;
    sred[wv][lane][1] = o1;
    sred[wv][lane][2] = o0 * o0;
    sred[wv][lane][3] = o1 * o1;
    __syncthreads();
    if (wv == 0) {
        float s0 = 0.f, s1 = 0.f, q0 = 0.f, q1 = 0.f;
#pragma unroll
        for (int g = 0; g < GAT_NPB; ++g) {
            s0 += sred[g][lane][0]; s1 += sred[g][lane][1];
            q0 += sred[g][lane][2]; q1 += sred[g][lane][3];
        }
        float* dst = bn1p + (blockIdx.x & (NSPLIT - 1)) * 256;
        int c0 = lane * 2;
        atomicAdd(&dst[c0], s0);
        atomicAdd(&dst[c0 + 1], s1);
        atomicAdd(&dst[128 + c0], q0);
        atomicAdd(&dst[128 + c0 + 1], q1);
    }
}

// ---------------- GIN aggregate with fused BN1+ELU on gathered rows --------------
__global__ __launch_bounds__(256) void k_gin_agg(const uint32* __restrict__ ob,
                                                 const int* __restrict__ row_ptr,
                                                 const int* __restrict__ sorted_src,
                                                 const float* __restrict__ eps_ptr,
                                                 const float* __restrict__ bn1p,
                                                 const float* __restrict__ gamma,
                                                 const float* __restrict__ beta,
                                                 uint32* __restrict__ zb) {
    __shared__ float stot[256];
    int t = threadIdx.x;
    float v = 0.f;
#pragma unroll
    for (int k = 0; k < NSPLIT; ++k) v += bn1p[k * 256 + t];
    stot[t] = v;
    __syncthreads();
    int lane = t & 63, wv = t >> 6;
    int c0 = lane * 2;
    float mu0 = stot[c0] * (1.f / N_NODES), mu1 = stot[c0 + 1] * (1.f / N_NODES);
    float va0 = stot[128 + c0] * (1.f / N_NODES) - mu0 * mu0;
    float va1 = stot[128 + c0 + 1] * (1.f / N_NODES) - mu1 * mu1;
    float s0 = rsqrtf(va0 + BN_EPS) * gamma[c0];
    float s1 = rsqrtf(va1 + BN_EPS) * gamma[c0 + 1];
    float h0 = beta[c0] - mu0 * s0;
    float h1 = beta[c0 + 1] - mu1 * s1;
    int node = blockIdx.x * 4 + wv;
    int start = row_ptr[node];
    int deg = row_ptr[node + 1] - start;
    float acc0 = 0.f, acc1 = 0.f;
    for (int j0 = 0; j0 < deg; j0 += 64) {
        int m = min(64, deg - j0);
        int s = 0;
        if (lane < m) s = sorted_src[start + j0 + lane];
        int e0 = 0;
        for (; e0 + 8 <= m; e0 += 8) {
            uint32 hr[8];
#pragma unroll
            for (int k = 0; k < 8; ++k) {
                int ss = __builtin_amdgcn_readlane(s, e0 + k);
                hr[k] = ob[((uint32)ss << 6) + lane];
            }
#pragma unroll
            for (int k = 0; k < 8; ++k) {
                float f0 = fmaf(bflo(hr[k]), s0, h0);
                float f1 = fmaf(bfhi(hr[k]), s1, h1);
                acc0 += f0 > 0.f ? f0 : __expf(f0) - 1.f;
                acc1 += f1 > 0.f ? f1 : __expf(f1) - 1.f;
            }
        }
        for (; e0 < m; ++e0) {
            int ss = __builtin_amdgcn_readlane(s, e0);
            uint32 hv = ob[((uint32)ss << 6) + lane];
            float f0 = fmaf(bflo(hv), s0, h0);
            float f1 = fmaf(bfhi(hv), s1, h1);
            acc0 += f0 > 0.f ? f0 : __expf(f0) - 1.f;
            acc1 += f1 > 0.f ? f1 : __expf(f1) - 1.f;
        }
    }
    float ep = 1.f + eps_ptr[0];
    uint32 own = ob[((uint32)node << 6) + lane];
    float f0 = fmaf(bflo(own), s0, h0);
    float f1 = fmaf(bfhi(own), s1, h1);
    f0 = f0 > 0.f ? f0 : __expf(f0) - 1.f;
    f1 = f1 > 0.f ? f1 : __expf(f1) - 1.f;
    zb[((uint32)node << 6) + lane] = packbf(fmaf(ep, f0, acc0), fmaf(ep, f1, acc1));
}

extern "C" void kernel_launch(void* const* d_in, const int* in_sizes, int n_in,
                              void* d_out, int out_size, void* d_ws, size_t ws_size,
                              hipStream_t stream) {
    (void)in_sizes; (void)n_in; (void)out_size; (void)ws_size;
    const float* x       = (const float*)d_in[0];
    const float* W_gat   = (const float*)d_in[1];
    const float* att_src = (const float*)d_in[2];
    const float* att_dst = (const float*)d_in[3];
    // bias_gat / lin_b cancel exactly under batch-norm -> dropped
    const float* bn1_g   = (const float*)d_in[5];
    const float* bn1_b   = (const float*)d_in[6];
    const float* eps_gin = (const float*)d_in[7];
    const float* lin_W   = (const float*)d_in[8];
    const float* bn2_g   = (const float*)d_in[10];
    const float* bn2_b   = (const float*)d_in[11];
    const int*   ei      = (const int*)d_in[12];
    float* out = (float*)d_out;

    char* w = (char*)d_ws;
    size_t o = 0;
    auto take = [&](size_t b) -> char* {
        char* p = w + o;
        o += (b + 255) & ~(size_t)255;
        return p;
    };
    unsigned short* hb   = (unsigned short*)take((size_t)N_NODES * 128 * 2);
    unsigned short* Wt1  = (unsigned short*)take((size_t)128 * IN_C * 2);
    unsigned short* Wt2  = (unsigned short*)take((size_t)128 * HID * 2);
    uint32* o1b          = (uint32*)take((size_t)N_NODES * 64 * 4);
    float* a_src         = (float*)take((size_t)N_NODES * 4 * 4);
    float* a_dst         = (float*)take((size_t)N_NODES * 4 * 4);
    int*   sorted        = (int*)take((size_t)N_EDGES * 4);
    int*   staging       = (int*)take((size_t)NBUCK * BPAD * 4);
    int*   row_ptr       = (int*)take((size_t)(N_NODES + 1) * 4);
    int*   gcursor       = (int*)take((NBUCK + 1) * 4);
    float* bnstat        = (float*)take((NSPLIT * 256 + 256) * 4); // bn1 partials + bn2
    float* bn1p          = bnstat;
    float* bn2acc        = bnstat + NSPLIT * 256;
    uint32* zb  = (uint32*)hb;  // reuse: hb dead after k_gat_agg
    uint32* o2b = o1b;          // fallback path only
    const int nGemmBlocks = (N_NODES + 127) / 128;

    hipMemsetAsync(gcursor, 0, (NBUCK + 1) * sizeof(int), stream);
    k_prep<<<NPART + TBLOCKS, 256, 0, stream>>>(ei, gcursor, staging, W_gat, lin_W,
                                                Wt1, Wt2, bnstat, row_ptr);
    k_gemm1_sort<<<NBUCK + nGemmBlocks, 256, 0, stream>>>(
        staging, gcursor, row_ptr, sorted, x, Wt1, hb, att_src, att_dst, a_src, a_dst);
    k_gat_agg<<<N_NODES / GAT_NPB, 512, 0, stream>>>((const uint32*)hb, a_src, a_dst,
                                                     row_ptr, sorted, o1b, bn1p);
    k_gin_agg<<<N_NODES / 4, 256, 0, stream>>>(o1b, row_ptr, sorted, eps_gin, bn1p,
                                               bn1_g, bn1_b, zb);

    // GEMM2+BN2+ELU: cooperative single-kernel if it fits, else 2-kernel fallback.
    bool coop = false;
    int maxb = 0;
    if (hipOccupancyMaxActiveBlocksPerMultiprocessor(&maxb, k_gemm2_bn, 256, 0) ==
            hipSuccess &&
        maxb * 256 >= nGemmBlocks) {   // 256 CUs on MI355X
        const void* zav = (const void*)zb;
        const unsigned short* wt2v = Wt2;
        float* bnv = bn2acc;
        const float* gv = bn2_g;
        const float* bv = bn2_b;
        float* fov = out;
        void* kargs[] = {&zav, &wt2v, &bnv, &gv, &bv, &fov};
        if (hipLaunchCooperativeKernel(k_gemm2_bn, dim3(nGemmBlocks), dim3(256),
                                       kargs, 0, stream) == hipSuccess)
            coop = true;
    }
    if (!coop) {
        k_gemm2<<<nGemmBlocks, 256, 0, stream>>>(zb, Wt2, o2b, bn2acc);
        k_bn_elu_out<<<ELEM_BLOCKS, 256, 0, stream>>>(o2b, bn2acc, bn2_g, bn2_b,
                                                      (float2*)out);
    }
}

// Round 11
// 466.102 us; speedup vs baseline: 1.0749x; 1.0001x over previous
//
#include <hip/hip_runtime.h>

#define N_NODES 100000
#define N_EDGES 1600000
#define IN_C 256
#define HID 128
#define NEG_SLOPE 0.2f
#define BN_EPS 1e-5f
#define NBUCK 391          // ceil(N_NODES/256): bucket b covers dst [b*256,(b+1)*256)
#define NPART 391          // ceil(N_EDGES/4096) partition tiles
#define PART_E 4096        // edges per partition block
#define BPAD 5120          // padded per-bucket staging stride (mean 4096 + 16 sigma)
#define TBLOCKS 192        // transpose blocks: (IN_C+HID)*128/256
#define NSPLIT 32          // BN1 partial-stat buffer copies
#define GAT_NPB 8          // nodes (waves) per gat block: halves stat-atomic count
#define ELEM_BLOCKS 2048   // grid-stride blocks for elementwise BN kernels

typedef unsigned int uint32;
typedef __attribute__((ext_vector_type(8))) short bf16x8;
typedef __attribute__((ext_vector_type(4))) float f32x4;

__device__ __forceinline__ float lrelu(float x) { return x > 0.f ? x : NEG_SLOPE * x; }

__device__ __forceinline__ unsigned short f2bf(float f) {
    uint32 u = __float_as_uint(f);
    u += 0x7fffu + ((u >> 16) & 1u);
    return (unsigned short)(u >> 16);
}
__device__ __forceinline__ float bf2f(unsigned short h) {
    return __uint_as_float(((uint32)h) << 16);
}
__device__ __forceinline__ float bflo(uint32 v) { return __uint_as_float(v << 16); }
__device__ __forceinline__ float bfhi(uint32 v) { return __uint_as_float(v & 0xffff0000u); }
__device__ __forceinline__ uint32 packbf(float a, float b) {
    return (uint32)f2bf(a) | ((uint32)f2bf(b) << 16);
}

// ================= GEMM device body ===============================================
// ATT:   fuse GAT attention dot-products into the epilogue.
// STATS: fuse BN column stats (sum, sumsq) into the epilogue.
// (R9's cooperative FUSEBN variant measured 105us vs ~45 for the 2-kernel pair:
//  grid.sync spin across XCDs + register cap. Reverted for good.)
template <bool AF32, bool OUTF32, bool ATT, bool STATS>
__device__ __forceinline__ void gemm_dev(int bid, const void* __restrict__ Av,
                                         const unsigned short* __restrict__ Wt,
                                         void* __restrict__ Out, int K,
                                         const float* __restrict__ att_s,
                                         const float* __restrict__ att_d,
                                         float* __restrict__ a_src,
                                         float* __restrict__ a_dst,
                                         float* __restrict__ bnst) {
    __shared__ unsigned short As[128 * 72];
    __shared__ unsigned short Bs[128 * 72];
    const int t = threadIdx.x;
    const int n0 = bid * 128;
    const int wv = t >> 6, lane = t & 63;
    const int wy = wv >> 1, wx = wv & 1;
    const int lm = lane & 15, lg = lane >> 4;
    const float* Af = (const float*)Av;
    const unsigned short* Ah = (const unsigned short*)Av;

    f32x4 acc[4][4];
#pragma unroll
    for (int i = 0; i < 4; ++i)
#pragma unroll
        for (int j = 0; j < 4; ++j) acc[i][j] = (f32x4){0.f, 0.f, 0.f, 0.f};

    float4 afp[8];
    uint4 ahp[4];
    uint4 bvp[4];

    if (AF32) {
#pragma unroll
        for (int p = 0; p < 8; ++p) {
            int idx = p * 256 + t, row = idx >> 4, c4 = idx & 15, gn = n0 + row;
            afp[p] = (gn < N_NODES) ? *(const float4*)&Af[(size_t)gn * K + c4 * 4]
                                    : make_float4(0.f, 0.f, 0.f, 0.f);
        }
    } else {
#pragma unroll
        for (int p = 0; p < 4; ++p) {
            int idx = p * 256 + t, row = idx >> 3, c = idx & 7, gn = n0 + row;
            ahp[p] = (gn < N_NODES) ? *(const uint4*)&Ah[(size_t)gn * K + c * 8]
                                    : make_uint4(0, 0, 0, 0);
        }
    }
#pragma unroll
    for (int p = 0; p < 4; ++p) {
        int idx = p * 256 + t, n = idx >> 3, c = idx & 7;
        bvp[p] = *(const uint4*)&Wt[(size_t)n * K + c * 8];
    }

    for (int kc = 0; kc < K; kc += 64) {
        if (AF32) {
#pragma unroll
            for (int p = 0; p < 8; ++p) {
                int idx = p * 256 + t, row = idx >> 4, c4 = idx & 15;
                ushort4 b;
                b.x = f2bf(afp[p].x); b.y = f2bf(afp[p].y);
                b.z = f2bf(afp[p].z); b.w = f2bf(afp[p].w);
                *(ushort4*)&As[row * 72 + c4 * 4] = b;
            }
        } else {
#pragma unroll
            for (int p = 0; p < 4; ++p) {
                int idx = p * 256 + t, row = idx >> 3, c = idx & 7;
                *(uint4*)&As[row * 72 + c * 8] = ahp[p];
            }
        }
#pragma unroll
        for (int p = 0; p < 4; ++p) {
            int idx = p * 256 + t, n = idx >> 3, c = idx & 7;
            *(uint4*)&Bs[n * 72 + c * 8] = bvp[p];
        }
        __syncthreads();
        int kn = kc + 64;
        if (kn < K) {
            if (AF32) {
#pragma unroll
                for (int p = 0; p < 8; ++p) {
                    int idx = p * 256 + t, row = idx >> 4, c4 = idx & 15, gn = n0 + row;
                    afp[p] = (gn < N_NODES) ? *(const float4*)&Af[(size_t)gn * K + kn + c4 * 4]
                                            : make_float4(0.f, 0.f, 0.f, 0.f);
                }
            } else {
#pragma unroll
                for (int p = 0; p < 4; ++p) {
                    int idx = p * 256 + t, row = idx >> 3, c = idx & 7, gn = n0 + row;
                    ahp[p] = (gn < N_NODES) ? *(const uint4*)&Ah[(size_t)gn * K + kn + c * 8]
                                            : make_uint4(0, 0, 0, 0);
                }
            }
#pragma unroll
            for (int p = 0; p < 4; ++p) {
                int idx = p * 256 + t, n = idx >> 3, c = idx & 7;
                bvp[p] = *(const uint4*)&Wt[(size_t)n * K + kn + c * 8];
            }
        }
#pragma unroll
        for (int ks = 0; ks < 2; ++ks) {
            bf16x8 af[4], bfr[4];
#pragma unroll
            for (int i = 0; i < 4; ++i)
                af[i] = *(const bf16x8*)&As[(wy * 64 + i * 16 + lm) * 72 + ks * 32 + lg * 8];
#pragma unroll
            for (int j = 0; j < 4; ++j)
                bfr[j] = *(const bf16x8*)&Bs[(wx * 64 + j * 16 + lm) * 72 + ks * 32 + lg * 8];
#pragma unroll
            for (int i = 0; i < 4; ++i)
#pragma unroll
                for (int j = 0; j < 4; ++j)
                    acc[i][j] = __builtin_amdgcn_mfma_f32_16x16x32_bf16(af[i], bfr[j],
                                                                        acc[i][j], 0, 0, 0);
        }
        __syncthreads();
    }

    // ---- epilogue ----
    float as_w[4], ad_w[4];
    if (ATT) {
#pragma unroll
        for (int j = 0; j < 4; ++j) {
            int col = wx * 64 + j * 16 + lm;
            as_w[j] = att_s[col];
            ad_w[j] = att_d[col];
        }
    }
    float ls[4] = {0.f, 0.f, 0.f, 0.f}, lq[4] = {0.f, 0.f, 0.f, 0.f};
#pragma unroll
    for (int i = 0; i < 4; ++i) {
#pragma unroll
        for (int r = 0; r < 4; ++r) {
            int row = n0 + wy * 64 + i * 16 + lg * 4 + r;
            float v0 = acc[i][0][r], v1 = acc[i][1][r];
            float v2 = acc[i][2][r], v3 = acc[i][3][r];
            if (row < N_NODES) {
                if (OUTF32) {
                    float* op = (float*)Out + (size_t)row * 128 + wx * 64 + lm;
                    op[0] = v0; op[16] = v1; op[32] = v2; op[48] = v3;
                } else {
                    unsigned short* op =
                        (unsigned short*)Out + (size_t)row * 128 + wx * 64 + lm;
                    op[0] = f2bf(v0); op[16] = f2bf(v1);
                    op[32] = f2bf(v2); op[48] = f2bf(v3);
                }
            }
            if (STATS) {  // padded rows contribute exact zeros (A zero-filled)
                ls[0] += v0; lq[0] += v0 * v0;
                ls[1] += v1; lq[1] += v1 * v1;
                ls[2] += v2; lq[2] += v2 * v2;
                ls[3] += v3; lq[3] += v3 * v3;
            }
            if (ATT) {
                float ps0 = v0 * as_w[0] + v1 * as_w[1];
                float ps1 = v2 * as_w[2] + v3 * as_w[3];
                float pd0 = v0 * ad_w[0] + v1 * ad_w[1];
                float pd1 = v2 * ad_w[2] + v3 * ad_w[3];
#pragma unroll
                for (int m = 1; m < 16; m <<= 1) {
                    ps0 += __shfl_xor(ps0, m); ps1 += __shfl_xor(ps1, m);
                    pd0 += __shfl_xor(pd0, m); pd1 += __shfl_xor(pd1, m);
                }
                if (lm == 0 && row < N_NODES) {
                    *(float2*)&a_src[row * 4 + wx * 2] = make_float2(ps0, ps1);
                    *(float2*)&a_dst[row * 4 + wx * 2] = make_float2(pd0, pd1);
                }
            }
        }
    }
    if (STATS) {
#pragma unroll
        for (int j = 0; j < 4; ++j) {
            float s = ls[j], q = lq[j];
            s += __shfl_xor(s, 16); s += __shfl_xor(s, 32);
            q += __shfl_xor(q, 16); q += __shfl_xor(q, 32);
            if (lg == 0) {
                int col = wx * 64 + j * 16 + lm;
                atomicAdd(&bnst[col], s);
                atomicAdd(&bnst[128 + col], q);
            }
        }
    }
}

// ================= bucket_sort device body ========================================
__device__ __forceinline__ void bucket_sort_dev(int b, const int* __restrict__ staging,
                                                const int* __restrict__ cnts,
                                                int* __restrict__ row_ptr,
                                                int* __restrict__ sorted_src) {
    __shared__ int hist[256];
    __shared__ int sh[256];
    __shared__ int spill[256][2];
    __shared__ int spill_cnt;
    __shared__ int obs[4];
    int t = threadIdx.x;
    int part = 0;
    for (int i = t; i < b; i += 256) part += cnts[i];
#pragma unroll
    for (int m = 1; m < 64; m <<= 1) part += __shfl_xor(part, m);
    if ((t & 63) == 0) obs[t >> 6] = part;
    int cnt = cnts[b];
    hist[t] = 0;
    if (t == 0) spill_cnt = 0;
    __syncthreads();
    int ob = obs[0] + obs[1] + obs[2] + obs[3];
    const int* sb = staging + b * BPAD;
    int ent[18], rnk[18];
#pragma unroll
    for (int u = 0; u < 18; ++u) {
        int i = u * 256 + t;
        ent[u] = -1;
        rnk[u] = 0;
        if (i < cnt) {
            int p = sb[i];
            ent[u] = p;
            rnk[u] = atomicAdd(&hist[p >> 17], 1);
        }
    }
    for (int i = 18 * 256 + t; i < cnt; i += 256) {
        int p = sb[i];
        int r = atomicAdd(&hist[p >> 17], 1);
        int si = atomicAdd(&spill_cnt, 1);
        spill[si][0] = p;
        spill[si][1] = r;
    }
    __syncthreads();
    int v0 = hist[t];
    int val = v0;
    sh[t] = val;
    __syncthreads();
    for (int off = 1; off < 256; off <<= 1) {
        int o = (t >= off) ? sh[t - off] : 0;
        __syncthreads();
        val += o;
        sh[t] = val;
        __syncthreads();
    }
    int excl = val - v0;
    int d = b * 256 + t;
    if (d < N_NODES) row_ptr[d] = ob + excl;
    __syncthreads();
    hist[t] = excl;
    __syncthreads();
#pragma unroll
    for (int u = 0; u < 18; ++u) {
        if (ent[u] >= 0) {
            int p = ent[u];
            sorted_src[ob + hist[p >> 17] + rnk[u]] = p & 0x1FFFF;
        }
    }
    for (int i = t; i < spill_cnt; i += 256) {
        int p = spill[i][0];
        sorted_src[ob + hist[p >> 17] + spill[i][1]] = p & 0x1FFFF;
    }
}

// ================= launch 1: partition (blocks 0..NPART-1) + transpose/init rest ==
__global__ __launch_bounds__(256) void k_prep(const int* __restrict__ ei,
                                              int* __restrict__ gcursor,
                                              int* __restrict__ staging,
                                              const float* __restrict__ W1,
                                              const float* __restrict__ W2,
                                              unsigned short* __restrict__ Wt1,
                                              unsigned short* __restrict__ Wt2,
                                              float* __restrict__ bnstat,
                                              int* __restrict__ row_ptr) {
    int t = threadIdx.x;
    if (blockIdx.x >= NPART) {
        int tb = blockIdx.x - NPART;
        int zi = tb * 256 + t;
        if (zi < NSPLIT * 256 + 256) bnstat[zi] = 0.f;
        if (zi == 0) row_ptr[N_NODES] = N_EDGES;
        int idx = tb * 256 + t;
        if (idx < IN_C * 128) {
            int k = idx >> 7, n = idx & 127;
            Wt1[n * IN_C + k] = f2bf(W1[idx]);
        } else {
            idx -= IN_C * 128;
            if (idx < HID * 128) {
                int k = idx >> 7, n = idx & 127;
                Wt2[n * HID + k] = f2bf(W2[idx]);
            }
        }
        return;
    }
    __shared__ int hist[NBUCK];
    __shared__ int loff[NBUCK];
    __shared__ int gbase[NBUCK];
    __shared__ int lstage[PART_E];
    __shared__ int gaddr[PART_E];
    __shared__ int scanbuf[512];
    int e0 = blockIdx.x * PART_E;
    int cntAll = min(PART_E, N_EDGES - e0);
    for (int i = t; i < NBUCK; i += 256) hist[i] = 0;
    __syncthreads();
    int pk[16];
    short bb[16], rr[16];
#pragma unroll
    for (int u = 0; u < 16; ++u) {
        int e = e0 + u * 256 + t;
        bb[u] = -1;
        rr[u] = 0;
        if (e < N_EDGES) {
            int s = ei[e], d = ei[N_EDGES + e];
            int b = d >> 8;
            int r = atomicAdd(&hist[b], 1);
            pk[u] = ((d & 255) << 17) | s;
            bb[u] = (short)b;
            rr[u] = (short)r;
        }
    }
    __syncthreads();
    scanbuf[t] = (t < NBUCK) ? hist[t] : 0;
    scanbuf[t + 256] = (t + 256 < NBUCK) ? hist[t + 256] : 0;
    __syncthreads();
    for (int off = 1; off < 512; off <<= 1) {
        int a0 = scanbuf[t];
        int a1 = scanbuf[t + 256];
        int b0 = (t >= off) ? scanbuf[t - off] : 0;
        int b1 = (t + 256 >= off) ? scanbuf[t + 256 - off] : 0;
        __syncthreads();
        scanbuf[t] = a0 + b0;
        scanbuf[t + 256] = a1 + b1;
        __syncthreads();
    }
    for (int i = t; i < NBUCK; i += 256) {
        loff[i] = scanbuf[i] - hist[i];
        gbase[i] = hist[i] ? atomicAdd(&gcursor[i], hist[i]) : 0;
    }
    __syncthreads();
#pragma unroll
    for (int u = 0; u < 16; ++u) {
        if (bb[u] >= 0) {
            int b = bb[u], r = rr[u];
            int pos = loff[b] + r;
            lstage[pos] = pk[u];
            gaddr[pos] = b * BPAD + gbase[b] + r;
        }
    }
    __syncthreads();
    for (int i = t; i < cntAll; i += 256) staging[gaddr[i]] = lstage[i];
}

// ================= launch 2: bucket_sort (blocks 0..NBUCK-1) || GEMM1 (rest) ======
__global__ __launch_bounds__(256) void k_gemm1_sort(const int* __restrict__ staging,
                                                    const int* __restrict__ cnts,
                                                    int* __restrict__ row_ptr,
                                                    int* __restrict__ sorted_src,
                                                    const float* __restrict__ x,
                                                    const unsigned short* __restrict__ Wt1,
                                                    unsigned short* __restrict__ hb,
                                                    const float* __restrict__ att_s,
                                                    const float* __restrict__ att_d,
                                                    float* __restrict__ a_src,
                                                    float* __restrict__ a_dst) {
    if (blockIdx.x < NBUCK) {
        bucket_sort_dev(blockIdx.x, staging, cnts, row_ptr, sorted_src);
    } else {
        gemm_dev<true, false, true, false>(blockIdx.x - NBUCK, x, Wt1, hb, IN_C,
                                           att_s, att_d, a_src, a_dst, nullptr);
    }
}

// ================= GEMM2 (fused BN2 stats) + separate BN/ELU output pass ==========
__global__ __launch_bounds__(256) void k_gemm2(const void* __restrict__ Av,
                                               const unsigned short* __restrict__ Wt,
                                               void* __restrict__ Out,
                                               float* __restrict__ bnst) {
    gemm_dev<false, false, false, true>(blockIdx.x, Av, Wt, Out, HID,
                                        nullptr, nullptr, nullptr, nullptr, bnst);
}

__global__ __launch_bounds__(256) void k_bn_elu_out(const uint32* __restrict__ in,
                                                    const float* __restrict__ acc,
                                                    const float* __restrict__ gamma,
                                                    const float* __restrict__ beta,
                                                    float2* __restrict__ out) {
    int t = threadIdx.x;
    int c0 = (t & 63) * 2;
    float mu0 = acc[c0] * (1.f / N_NODES), mu1 = acc[c0 + 1] * (1.f / N_NODES);
    float va0 = acc[128 + c0] * (1.f / N_NODES) - mu0 * mu0;
    float va1 = acc[128 + c0 + 1] * (1.f / N_NODES) - mu1 * mu1;
    float s0 = rsqrtf(va0 + BN_EPS) * gamma[c0];
    float s1 = rsqrtf(va1 + BN_EPS) * gamma[c0 + 1];
    float h0 = beta[c0] - mu0 * s0;
    float h1 = beta[c0 + 1] - mu1 * s1;
    for (size_t i = (size_t)blockIdx.x * 256 + t; i < (size_t)N_NODES * 64;
         i += (size_t)ELEM_BLOCKS * 256) {
        uint32 v = in[i];
        float r0 = fmaf(bflo(v), s0, h0);
        float r1 = fmaf(bfhi(v), s1, h1);
        r0 = r0 > 0.f ? r0 : __expf(r0) - 1.f;
        r1 = r1 > 0.f ? r1 : __expf(r1) - 1.f;
        out[i] = make_float2(r0, r1);
    }
}

// ---------------- GAT aggregate + fused BN1 stats, 8 waves/block ------------------
// Per-wave gather structure IDENTICAL to the proven shape (1 node/wave, same inner
// loops). 8 nodes/block halves the device-atomic count (12500 x 256 = 3.2M).
__global__ __launch_bounds__(512) void k_gat_agg(const uint32* __restrict__ h32,
                                                 const float* __restrict__ a_src,
                                                 const float* __restrict__ a_dst,
                                                 const int* __restrict__ row_ptr,
                                                 const int* __restrict__ sorted_src,
                                                 uint32* __restrict__ out1,
                                                 float* __restrict__ bn1p) {
    __shared__ alignas(16) float wbuf[GAT_NPB][4][72];   // [wave][head][edge]
    __shared__ float sred[GAT_NPB][64][4];
    int lane = threadIdx.x & 63, wv = threadIdx.x >> 6;
    int hd = lane >> 4;
    int node = blockIdx.x * GAT_NPB + wv;
    int start = row_ptr[node];
    int deg = row_ptr[node + 1] - start;
    float o0 = 0.f, o1 = 0.f;
    if (deg != 0) {
        float4 ad = *(const float4*)&a_dst[node * 4];
        float acc0 = 0.f, acc1 = 0.f, den = 0.f;
        for (int j0 = 0; j0 < deg; j0 += 64) {
            int m = min(64, deg - j0);
            int s = 0;
            float4 w = make_float4(0.f, 0.f, 0.f, 0.f);
            if (lane < m) {
                s = sorted_src[start + j0 + lane];
                float4 as = *(const float4*)&a_src[s * 4];
                w.x = __expf(lrelu(as.x + ad.x));
                w.y = __expf(lrelu(as.y + ad.y));
                w.z = __expf(lrelu(as.z + ad.z));
                w.w = __expf(lrelu(as.w + ad.w));
            }
            wbuf[wv][0][lane] = w.x;
            wbuf[wv][1][lane] = w.y;
            wbuf[wv][2][lane] = w.z;
            wbuf[wv][3][lane] = w.w;
            __builtin_amdgcn_wave_barrier();
            int e0 = 0;
            for (; e0 + 8 <= m; e0 += 8) {
                uint32 hr[8];
#pragma unroll
                for (int k = 0; k < 8; ++k) {
                    int ss = __builtin_amdgcn_readlane(s, e0 + k);
                    hr[k] = h32[((uint32)ss << 6) + lane];
                }
                float4 w0 = *(const float4*)&wbuf[wv][hd][e0];
                float4 w1 = *(const float4*)&wbuf[wv][hd][e0 + 4];
                float wk[8] = {w0.x, w0.y, w0.z, w0.w, w1.x, w1.y, w1.z, w1.w};
#pragma unroll
                for (int k = 0; k < 8; ++k) {
                    den += wk[k];
                    acc0 = fmaf(wk[k], bflo(hr[k]), acc0);
                    acc1 = fmaf(wk[k], bfhi(hr[k]), acc1);
                }
            }
            for (; e0 < m; ++e0) {
                int ss = __builtin_amdgcn_readlane(s, e0);
                uint32 hv = h32[((uint32)ss << 6) + lane];
                float wk = wbuf[wv][hd][e0];
                den += wk;
                acc0 = fmaf(wk, bflo(hv), acc0);
                acc1 = fmaf(wk, bfhi(hv), acc1);
            }
            __builtin_amdgcn_wave_barrier();
        }
        float rden = 1.f / den;
        o0 = acc0 * rden;
        o1 = acc1 * rden;
    }
    out1[((uint32)node << 6) + lane] = packbf(o0, o1);
    sred[wv][lane][0] = o0;
    sred[wv][lane][1] = o1;
    sred[wv][lane][2] = o0 * o0;
    sred[wv][lane][3] = o1 * o1;
    __syncthreads();
    if (wv == 0) {
        float s0 = 0.f, s1 = 0.f, q0 = 0.f, q1 = 0.f;
#pragma unroll
        for (int g = 0; g < GAT_NPB; ++g) {
            s0 += sred[g][lane][0]; s1 += sred[g][lane][1];
            q0 += sred[g][lane][2]; q1 += sred[g][lane][3];
        }
        float* dst = bn1p + (blockIdx.x & (NSPLIT - 1)) * 256;
        int c0 = lane * 2;
        atomicAdd(&dst[c0], s0);
        atomicAdd(&dst[c0 + 1], s1);
        atomicAdd(&dst[128 + c0], q0);
        atomicAdd(&dst[128 + c0 + 1], q1);
    }
}

// ---------------- GIN aggregate with fused BN1+ELU on gathered rows --------------
__global__ __launch_bounds__(256) void k_gin_agg(const uint32* __restrict__ ob,
                                                 const int* __restrict__ row_ptr,
                                                 const int* __restrict__ sorted_src,
                                                 const float* __restrict__ eps_ptr,
                                                 const float* __restrict__ bn1p,
                                                 const float* __restrict__ gamma,
                                                 const float* __restrict__ beta,
                                                 uint32* __restrict__ zb) {
    __shared__ float stot[256];
    int t = threadIdx.x;
    float v = 0.f;
#pragma unroll
    for (int k = 0; k < NSPLIT; ++k) v += bn1p[k * 256 + t];
    stot[t] = v;
    __syncthreads();
    int lane = t & 63, wv = t >> 6;
    int c0 = lane * 2;
    float mu0 = stot[c0] * (1.f / N_NODES), mu1 = stot[c0 + 1] * (1.f / N_NODES);
    float va0 = stot[128 + c0] * (1.f / N_NODES) - mu0 * mu0;
    float va1 = stot[128 + c0 + 1] * (1.f / N_NODES) - mu1 * mu1;
    float s0 = rsqrtf(va0 + BN_EPS) * gamma[c0];
    float s1 = rsqrtf(va1 + BN_EPS) * gamma[c0 + 1];
    float h0 = beta[c0] - mu0 * s0;
    float h1 = beta[c0 + 1] - mu1 * s1;
    int node = blockIdx.x * 4 + wv;
    int start = row_ptr[node];
    int deg = row_ptr[node + 1] - start;
    float acc0 = 0.f, acc1 = 0.f;
    for (int j0 = 0; j0 < deg; j0 += 64) {
        int m = min(64, deg - j0);
        int s = 0;
        if (lane < m) s = sorted_src[start + j0 + lane];
        int e0 = 0;
        for (; e0 + 8 <= m; e0 += 8) {
            uint32 hr[8];
#pragma unroll
            for (int k = 0; k < 8; ++k) {
                int ss = __builtin_amdgcn_readlane(s, e0 + k);
                hr[k] = ob[((uint32)ss << 6) + lane];
            }
#pragma unroll
            for (int k = 0; k < 8; ++k) {
                float f0 = fmaf(bflo(hr[k]), s0, h0);
                float f1 = fmaf(bfhi(hr[k]), s1, h1);
                acc0 += f0 > 0.f ? f0 : __expf(f0) - 1.f;
                acc1 += f1 > 0.f ? f1 : __expf(f1) - 1.f;
            }
        }
        for (; e0 < m; ++e0) {
            int ss = __builtin_amdgcn_readlane(s, e0);
            uint32 hv = ob[((uint32)ss << 6) + lane];
            float f0 = fmaf(bflo(hv), s0, h0);
            float f1 = fmaf(bfhi(hv), s1, h1);
            acc0 += f0 > 0.f ? f0 : __expf(f0) - 1.f;
            acc1 += f1 > 0.f ? f1 : __expf(f1) - 1.f;
        }
    }
    float ep = 1.f + eps_ptr[0];
    uint32 own = ob[((uint32)node << 6) + lane];
    float f0 = fmaf(bflo(own), s0, h0);
    float f1 = fmaf(bfhi(own), s1, h1);
    f0 = f0 > 0.f ? f0 : __expf(f0) - 1.f;
    f1 = f1 > 0.f ? f1 : __expf(f1) - 1.f;
    zb[((uint32)node << 6) + lane] = packbf(fmaf(ep, f0, acc0), fmaf(ep, f1, acc1));
}

extern "C" void kernel_launch(void* const* d_in, const int* in_sizes, int n_in,
                              void* d_out, int out_size, void* d_ws, size_t ws_size,
                              hipStream_t stream) {
    (void)in_sizes; (void)n_in; (void)out_size; (void)ws_size;
    const float* x       = (const float*)d_in[0];
    const float* W_gat   = (const float*)d_in[1];
    const float* att_src = (const float*)d_in[2];
    const float* att_dst = (const float*)d_in[3];
    // bias_gat / lin_b cancel exactly under batch-norm -> dropped
    const float* bn1_g   = (const float*)d_in[5];
    const float* bn1_b   = (const float*)d_in[6];
    const float* eps_gin = (const float*)d_in[7];
    const float* lin_W   = (const float*)d_in[8];
    const float* bn2_g   = (const float*)d_in[10];
    const float* bn2_b   = (const float*)d_in[11];
    const int*   ei      = (const int*)d_in[12];
    float* out = (float*)d_out;

    char* w = (char*)d_ws;
    size_t o = 0;
    auto take = [&](size_t b) -> char* {
        char* p = w + o;
        o += (b + 255) & ~(size_t)255;
        return p;
    };
    unsigned short* hb   = (unsigned short*)take((size_t)N_NODES * 128 * 2);
    unsigned short* Wt1  = (unsigned short*)take((size_t)128 * IN_C * 2);
    unsigned short* Wt2  = (unsigned short*)take((size_t)128 * HID * 2);
    uint32* o1b          = (uint32*)take((size_t)N_NODES * 64 * 4);
    float* a_src         = (float*)take((size_t)N_NODES * 4 * 4);
    float* a_dst         = (float*)take((size_t)N_NODES * 4 * 4);
    int*   sorted        = (int*)take((size_t)N_EDGES * 4);
    int*   staging       = (int*)take((size_t)NBUCK * BPAD * 4);
    int*   row_ptr       = (int*)take((size_t)(N_NODES + 1) * 4);
    int*   gcursor       = (int*)take((NBUCK + 1) * 4);
    float* bnstat        = (float*)take((NSPLIT * 256 + 256) * 4); // bn1 partials + bn2
    float* bn1p          = bnstat;
    float* bn2acc        = bnstat + NSPLIT * 256;
    uint32* zb  = (uint32*)hb;  // reuse: hb dead after k_gat_agg
    uint32* o2b = o1b;          // reuse: o1b dead after k_gin_agg reads it
    const int nGemmBlocks = (N_NODES + 127) / 128;

    hipMemsetAsync(gcursor, 0, (NBUCK + 1) * sizeof(int), stream);
    k_prep<<<NPART + TBLOCKS, 256, 0, stream>>>(ei, gcursor, staging, W_gat, lin_W,
                                                Wt1, Wt2, bnstat, row_ptr);
    k_gemm1_sort<<<NBUCK + nGemmBlocks, 256, 0, stream>>>(
        staging, gcursor, row_ptr, sorted, x, Wt1, hb, att_src, att_dst, a_src, a_dst);
    k_gat_agg<<<N_NODES / GAT_NPB, 512, 0, stream>>>((const uint32*)hb, a_src, a_dst,
                                                     row_ptr, sorted, o1b, bn1p);
    k_gin_agg<<<N_NODES / 4, 256, 0, stream>>>(o1b, row_ptr, sorted, eps_gin, bn1p,
                                               bn1_g, bn1_b, zb);
    k_gemm2<<<nGemmBlocks, 256, 0, stream>>>(zb, Wt2, o2b, bn2acc);
    k_bn_elu_out<<<ELEM_BLOCKS, 256, 0, stream>>>(o2b, bn2acc, bn2_g, bn2_b,
                                                  (float2*)out);
}